// Round 9
// baseline (223.673 us; speedup 1.0000x reference)
//
#include <hip/hip_runtime.h>

typedef _Float16 half8 __attribute__((ext_vector_type(8)));
typedef _Float16 half4 __attribute__((ext_vector_type(4)));
typedef _Float16 half2v __attribute__((ext_vector_type(2)));
typedef float f32x4 __attribute__((ext_vector_type(4)));

#define B_    16
#define N_    1024
#define D_    768
#define H_    12
#define M_    (B_ * N_)     // 16384
#define QKVN_ 2304
#define EPS_  1e-5f
#define QS_   0.18033688011112042f   // 0.125 * log2(e)

__device__ __forceinline__ float exp2_fast(float x) {
#if __has_builtin(__builtin_amdgcn_exp2f)
    return __builtin_amdgcn_exp2f(x);
#else
    return __builtin_exp2f(x);
#endif
}

// fragment-pack offset (halves): [t16][kc=24][lg=4][p=16][e=8]
// packed[t16][kc][lg][p][e] = ROWMAJOR[t16*16 + p][kc*32 + lg*8 + e]
__device__ __forceinline__ size_t pk(int t16, int kc, int lg, int p, int e) {
    return ((size_t)(t16 * 24 + kc) * 4 + lg) * 128 + p * 8 + e;
}

// ---------------- weight cast + fragment pack (LDS-tiled, coalesced both sides) ----------
__global__ __launch_bounds__(256) void convert_w(const float* __restrict__ Wqkv,
                                                 const float* __restrict__ Wproj,
                                                 _Float16* __restrict__ wqkv_p,
                                                 _Float16* __restrict__ wproj_p) {
    __shared__ float T[64][65];                 // T[n_local][k_local]
    int t = blockIdx.x;
    const float* W; _Float16* O; int NW, k0, n0;
    if (t < 432) { W = Wqkv;  O = wqkv_p;  NW = QKVN_; k0 = (t % 12) * 64; n0 = (t / 12) * 64; }
    else { t -= 432; W = Wproj; O = wproj_p; NW = D_;  k0 = (t % 12) * 64; n0 = (t / 12) * 64; }
    int c = threadIdx.x & 63, r4 = threadIdx.x >> 6;
#pragma unroll
    for (int i = 0; i < 16; ++i) {
        int k = i * 4 + r4;
        T[c][k] = W[(size_t)(k0 + k) * NW + n0 + c];
    }
    __syncthreads();
    int g = threadIdx.x >> 5, s2 = threadIdx.x & 31;
    int ntl = g & 3, kcl = g >> 2;
    int nt = (n0 >> 4) + ntl, kc = (k0 >> 5) + kcl;
#pragma unroll
    for (int hh = 0; hh < 2; ++hh) {
        int s = s2 + hh * 32;
        int lg = s >> 4, p = s & 15;
        half8 v;
#pragma unroll
        for (int e = 0; e < 8; ++e)
            v[e] = (_Float16)T[ntl * 16 + p][kcl * 32 + lg * 8 + e];
        *(half8*)&O[((size_t)(nt * 24 + kc) * 4 + lg) * 128 + p * 8] = v;
    }
}

// ---------------- embed LayerNorm -> xn packed A-fragment-major ----------------
__global__ __launch_bounds__(256) void ln_embed(const float* __restrict__ x,
                                                const float* __restrict__ g,
                                                const float* __restrict__ bb,
                                                _Float16* __restrict__ xp) {
    int row = blockIdx.x;
    int tid = threadIdx.x;
    const float2* xr = (const float2*)(x + (size_t)row * D_);
    float2 v0 = xr[tid];
    float2 v1 = make_float2(0.f, 0.f);
    if (tid < 128) v1 = xr[256 + tid];
    float s = v0.x + v0.y + v1.x + v1.y;
    float q = v0.x * v0.x + v0.y * v0.y + v1.x * v1.x + v1.y * v1.y;
#pragma unroll
    for (int m = 32; m >= 1; m >>= 1) {
        s += __shfl_xor(s, m);
        q += __shfl_xor(q, m);
    }
    __shared__ float ss[4], qq[4];
    int wave = tid >> 6;
    if ((tid & 63) == 0) { ss[wave] = s; qq[wave] = q; }
    __syncthreads();
    float S = ss[0] + ss[1] + ss[2] + ss[3];
    float Q = qq[0] + qq[1] + qq[2] + qq[3];
    float mean = S * (1.f / 768.f);
    float var  = Q * (1.f / 768.f) - mean * mean;
    float rstd = rsqrtf(var + EPS_);
    const float2* g2 = (const float2*)g;
    const float2* b2 = (const float2*)bb;
    int mt = row >> 4, p = row & 15;
    {
        int d0 = 2 * tid;
        float2 ga = g2[tid], ba = b2[tid];
        half2v w;
        w[0] = (_Float16)((v0.x - mean) * rstd * ga.x + ba.x);
        w[1] = (_Float16)((v0.y - mean) * rstd * ga.y + ba.y);
        *(half2v*)&xp[pk(mt, d0 >> 5, (d0 >> 3) & 3, p, d0 & 7)] = w;
    }
    if (tid < 128) {
        int d0 = 512 + 2 * tid;
        float2 ga = g2[256 + tid], ba = b2[256 + tid];
        half2v w;
        w[0] = (_Float16)((v1.x - mean) * rstd * ga.x + ba.x);
        w[1] = (_Float16)((v1.y - mean) * rstd * ga.y + ba.y);
        *(half2v*)&xp[pk(mt, d0 >> 5, (d0 >> 3) & 3, p, d0 & 7)] = w;
    }
}

// ---------------- QKV GEMM: 256x128 block, per-wave 128x64, pure-register ----------------
// 43.7 FLOP per L1 byte (vs 32.8 at 128^2): A/B each pulled 2x per block-K-step,
// but per-wave tile is 2x taller. Depth-1 ping-pong, 2 waves/SIMD.
__global__ __launch_bounds__(256, 2) void gemm_qkv(const _Float16* __restrict__ Ap,
                                                   const _Float16* __restrict__ Bp,
                                                   const float* __restrict__ bias,
                                                   const float* __restrict__ qn_g,
                                                   const float* __restrict__ qn_b,
                                                   const float* __restrict__ kn_g,
                                                   const float* __restrict__ kn_b,
                                                   _Float16* __restrict__ qo,
                                                   _Float16* __restrict__ ko,
                                                   _Float16* __restrict__ vt) {
    int xcd = blockIdx.x & 7, loc = blockIdx.x >> 3;     // 1152 = 8 XCD * (8 m * 18 n)
    int mt0 = (xcd * 8 + (loc & 7)) * 16;                // t16 units; m fastest within XCD
    int nt0 = (loc >> 3) * 8;
    int tid = threadIdx.x;
    int wave = tid >> 6, lane = tid & 63;
    int wm = wave >> 1, wn = wave & 1;
    int lg = lane >> 4, l15 = lane & 15;

    const _Float16* pa = Ap + (size_t)(mt0 + wm * 8) * 12288 + lane * 8;
    const _Float16* pb = Bp + (size_t)(nt0 + wn * 4) * 12288 + lane * 8;

    f32x4 acc[8][4] = {};
    half8 a0[8], b0[4], a1[8], b1[4];
    auto ld = [&](half8 (&a)[8], half8 (&b)[4], int t) {
        int off = t * 512;
#pragma unroll
        for (int i = 0; i < 8; ++i) a[i] = *(const half8*)(pa + (size_t)i * 12288 + off);
#pragma unroll
        for (int i = 0; i < 4; ++i) b[i] = *(const half8*)(pb + (size_t)i * 12288 + off);
    };
    auto mm = [&](half8 (&a)[8], half8 (&b)[4]) {
#pragma unroll
        for (int mi = 0; mi < 8; ++mi)
#pragma unroll
            for (int ni = 0; ni < 4; ++ni)
                acc[mi][ni] = __builtin_amdgcn_mfma_f32_16x16x32_f16(a[mi], b[ni], acc[mi][ni], 0, 0, 0);
    };
    ld(a0, b0, 0);
    for (int tt = 0; tt < 11; ++tt) {
        ld(a1, b1, 2 * tt + 1);
        mm(a0, b0);
        ld(a0, b0, 2 * tt + 2);
        mm(a1, b1);
    }
    ld(a1, b1, 23);
    mm(a0, b0);
    mm(a1, b1);

    // ---- epilogue: fused per-head LN + fragment-major scatter (per-wave 128 rows x 64 cols)
    int m0 = mt0 * 16, n0 = nt0 * 16;
    int col0 = n0 + wn * 64;
    int s = col0 / 768;
    int hcol = (col0 % 768) >> 6;
    float qkvb[4];
#pragma unroll
    for (int ni = 0; ni < 4; ++ni) qkvb[ni] = bias[col0 + ni * 16 + l15];

    if (s == 2) {
#pragma unroll
        for (int mi = 0; mi < 8; ++mi) {
            int r0 = m0 + wm * 128 + mi * 16 + lg * 4;
            int bidx = r0 >> 10, pos = r0 & 1023;
            int kvblk = pos >> 5, h = (pos >> 4) & 1, lgR = (pos >> 2) & 3;
            size_t vbase = ((size_t)(bidx * H_ + hcol) * 32 + kvblk) * 4;
#pragma unroll
            for (int ni = 0; ni < 4; ++ni) {
                half4 h4;
#pragma unroll
                for (int j = 0; j < 4; ++j) h4[j] = (_Float16)(acc[mi][ni][j] + qkvb[ni]);
                *(half4*)&vt[(vbase + ni) * 512 + lgR * 128 + l15 * 8 + h * 4] = h4;
            }
        }
    } else {
        const float* gg = (s == 0) ? qn_g : kn_g;
        const float* bb = (s == 0) ? qn_b : kn_b;
        float gv[4], bv[4];
#pragma unroll
        for (int ni = 0; ni < 4; ++ni) { gv[ni] = gg[ni * 16 + l15]; bv[ni] = bb[ni * 16 + l15]; }
#pragma unroll
        for (int mi = 0; mi < 8; ++mi) {
#pragma unroll
            for (int j = 0; j < 4; ++j) {
                float v[4];
                float sm = 0.f, sq = 0.f;
#pragma unroll
                for (int ni = 0; ni < 4; ++ni) {
                    v[ni] = acc[mi][ni][j] + qkvb[ni];
                    sm += v[ni];
                    sq += v[ni] * v[ni];
                }
#pragma unroll
                for (int msk = 1; msk < 16; msk <<= 1) {
                    sm += __shfl_xor(sm, msk);
                    sq += __shfl_xor(sq, msk);
                }
                float mean = sm * (1.f / 64.f);
                float var  = sq * (1.f / 64.f) - mean * mean;
                float rstd = rsqrtf(var + EPS_);
                int row = m0 + wm * 128 + mi * 16 + lg * 4 + j;
                int bidx = row >> 10, pos = row & 1023;
                if (s == 0) {
                    size_t rbase = ((size_t)(bidx * H_ + hcol) * 1024 + pos) * 64;
#pragma unroll
                    for (int ni = 0; ni < 4; ++ni) {
                        float o = (v[ni] - mean) * rstd * gv[ni] + bv[ni];
                        qo[rbase + ni * 16 + l15] = (_Float16)(o * QS_);
                    }
                } else {
                    int kvblk = pos >> 5, nh = (pos >> 4) & 1, l15R = pos & 15;
                    size_t base2 = ((size_t)(bidx * H_ + hcol) * 32 + kvblk) * 4 + nh * 2;
#pragma unroll
                    for (int ni = 0; ni < 4; ++ni) {
                        float o = (v[ni] - mean) * rstd * gv[ni] + bv[ni];
                        int ks = ni >> 1, lgR = ((ni & 1) << 1) | (l15 >> 3), elem = l15 & 7;
                        ko[(base2 + ks) * 512 + lgR * 128 + l15R * 8 + elem] = (_Float16)o;
                    }
                }
            }
        }
    }
}

// ---------------- flash attention: pure-register; output packed for proj-A ----------
struct KV {
    half8 kf[2][2];   // [nh][ks]
    half8 vf[4];      // [di]
};

__device__ __forceinline__ void ldKV(KV& s, const _Float16* kp, const _Float16* vp, int kvblk) {
    const _Float16* kb = kp + (size_t)kvblk * 2048;
#pragma unroll
    for (int nh = 0; nh < 2; ++nh)
#pragma unroll
        for (int ks = 0; ks < 2; ++ks)
            s.kf[nh][ks] = *(const half8*)(kb + (nh * 2 + ks) * 512);
    const _Float16* vb = vp + (size_t)kvblk * 2048;
#pragma unroll
    for (int di = 0; di < 4; ++di)
        s.vf[di] = *(const half8*)(vb + di * 512);
}

__device__ __forceinline__ void blockKV(const KV& s, const half8 (&qf)[4][2],
                                        f32x4 (&oacc)[4][4], f32x4 (&lacc)[4],
                                        half8 ones) {
#pragma unroll
    for (int mi = 0; mi < 4; ++mi) {
        f32x4 a0 = {}, a1 = {};
#pragma unroll
        for (int ks = 0; ks < 2; ++ks) {
            a0 = __builtin_amdgcn_mfma_f32_16x16x32_f16(s.kf[0][ks], qf[mi][ks], a0, 0, 0, 0);
            a1 = __builtin_amdgcn_mfma_f32_16x16x32_f16(s.kf[1][ks], qf[mi][ks], a1, 0, 0, 0);
        }
        half8 pf;
#pragma unroll
        for (int j = 0; j < 4; ++j) {
            pf[j]     = (_Float16)exp2_fast(a0[j]);
            pf[j + 4] = (_Float16)exp2_fast(a1[j]);
        }
        lacc[mi] = __builtin_amdgcn_mfma_f32_16x16x32_f16(ones, pf, lacc[mi], 0, 0, 0);
#pragma unroll
        for (int di = 0; di < 4; ++di)
            oacc[mi][di] = __builtin_amdgcn_mfma_f32_16x16x32_f16(s.vf[di], pf, oacc[mi][di], 0, 0, 0);
    }
}

__global__ __launch_bounds__(128, 2) void attn(const _Float16* __restrict__ qg,
                                               const _Float16* __restrict__ kg,
                                               const _Float16* __restrict__ vtg,
                                               _Float16* __restrict__ op) {
    int bphys = blockIdx.x;                          // 0..1535
    int jj = (bphys & 7) * 192 + (bphys >> 3);       // XCD swizzle
    int bh = jj >> 3, qt = jj & 7;
    int b = bh / H_, h = bh % H_;
    int tid = threadIdx.x;
    int wid = tid >> 6, lane = tid & 63;
    int lg = lane >> 4, l15 = lane & 15;
    size_t base = (size_t)bh << 10;
    int qw0 = qt * 128 + wid * 64;

    const _Float16* qrow = qg + (base + qw0 + l15) * 64 + lg * 8;
    half8 qf[4][2];
#pragma unroll
    for (int mi = 0; mi < 4; ++mi)
#pragma unroll
        for (int ks = 0; ks < 2; ++ks)
            qf[mi][ks] = *(const half8*)(qrow + mi * 1024 + ks * 32);

    const _Float16* kp = kg + (size_t)bh * 65536 + lane * 8;
    const _Float16* vp = vtg + (size_t)bh * 65536 + lane * 8;

    half8 ones;
#pragma unroll
    for (int i = 0; i < 8; ++i) ones[i] = (_Float16)1.0f;

    f32x4 oacc[4][4] = {};
    f32x4 lacc[4] = {};

    KV s0, s1;
    ldKV(s0, kp, vp, 0);
    for (int t = 0; t < 16; ++t) {
        ldKV(s1, kp, vp, (2 * t + 1) & 31);
        blockKV(s0, qf, oacc, lacc, ones);
        ldKV(s0, kp, vp, (2 * t + 2) & 31);
        blockKV(s1, qf, oacc, lacc, ones);
    }

    // write O packed as gemm_proj A-fragments: k = 64h + di*16 + lg*4 + j
#pragma unroll
    for (int mi = 0; mi < 4; ++mi) {
        float inv = 1.f / lacc[mi][0];
        int mt = b * 64 + (qw0 >> 4) + mi;
#pragma unroll
        for (int di = 0; di < 4; ++di) {
            half4 h4;
#pragma unroll
            for (int j = 0; j < 4; ++j) h4[j] = (_Float16)(oacc[mi][di][j] * inv);
            *(half4*)&op[pk(mt, 2 * h + (di >> 1), (di & 1) * 2 + (lg >> 1), l15, (lg & 1) * 4)] = h4;
        }
    }
}

// ---------------- proj GEMM: 256x128 block, per-wave 128x64, pure-register --------------
__global__ __launch_bounds__(256, 2) void gemm_proj(const _Float16* __restrict__ Ap,
                                                    const _Float16* __restrict__ Bp,
                                                    const float* __restrict__ bias,
                                                    float* __restrict__ out) {
    int xcd = blockIdx.x & 7, loc = blockIdx.x >> 3;     // 384 = 8 XCD * (8 m * 6 n)
    int mt0 = (xcd * 8 + (loc & 7)) * 16;
    int nt0 = (loc >> 3) * 8;
    int tid = threadIdx.x;
    int wave = tid >> 6, lane = tid & 63;
    int wm = wave >> 1, wn = wave & 1;
    int lg = lane >> 4, l15 = lane & 15;

    const _Float16* pa = Ap + (size_t)(mt0 + wm * 8) * 12288 + lane * 8;
    const _Float16* pb = Bp + (size_t)(nt0 + wn * 4) * 12288 + lane * 8;

    f32x4 acc[8][4] = {};
    half8 a0[8], b0[4], a1[8], b1[4];
    auto ld = [&](half8 (&a)[8], half8 (&b)[4], int t) {
        int off = t * 512;
#pragma unroll
        for (int i = 0; i < 8; ++i) a[i] = *(const half8*)(pa + (size_t)i * 12288 + off);
#pragma unroll
        for (int i = 0; i < 4; ++i) b[i] = *(const half8*)(pb + (size_t)i * 12288 + off);
    };
    auto mm = [&](half8 (&a)[8], half8 (&b)[4]) {
#pragma unroll
        for (int mi = 0; mi < 8; ++mi)
#pragma unroll
            for (int ni = 0; ni < 4; ++ni)
                acc[mi][ni] = __builtin_amdgcn_mfma_f32_16x16x32_f16(a[mi], b[ni], acc[mi][ni], 0, 0, 0);
    };
    ld(a0, b0, 0);
    for (int tt = 0; tt < 11; ++tt) {
        ld(a1, b1, 2 * tt + 1);
        mm(a0, b0);
        ld(a0, b0, 2 * tt + 2);
        mm(a1, b1);
    }
    ld(a1, b1, 23);
    mm(a0, b0);
    mm(a1, b1);

    int m0 = mt0 * 16, n0 = nt0 * 16;
#pragma unroll
    for (int mi = 0; mi < 8; ++mi)
#pragma unroll
        for (int ni = 0; ni < 4; ++ni) {
            int col = n0 + wn * 64 + ni * 16 + l15;
            float bv = bias[col];
#pragma unroll
            for (int j = 0; j < 4; ++j) {
                int row = m0 + wm * 128 + mi * 16 + lg * 4 + j;
                out[(size_t)row * D_ + col] = acc[mi][ni][j] + bv;
            }
        }
}

// ---------------- launch ----------------
extern "C" void kernel_launch(void* const* d_in, const int* in_sizes, int n_in,
                              void* d_out, int out_size, void* d_ws, size_t ws_size,
                              hipStream_t stream) {
    const float* x      = (const float*)d_in[0];
    const float* ln_g   = (const float*)d_in[1];
    const float* ln_b   = (const float*)d_in[2];
    const float* W_qkv  = (const float*)d_in[3];
    const float* b_qkv  = (const float*)d_in[4];
    const float* qn_g   = (const float*)d_in[5];
    const float* qn_b   = (const float*)d_in[6];
    const float* kn_g   = (const float*)d_in[7];
    const float* kn_b   = (const float*)d_in[8];
    const float* W_proj = (const float*)d_in[9];
    const float* b_proj = (const float*)d_in[10];
    float* out = (float*)d_out;
    char* ws = (char*)d_ws;

    constexpr size_t XN_SZ    = (size_t)M_ * D_ * 2;
    constexpr size_t WQKVT_SZ = (size_t)QKVN_ * D_ * 2;
    constexpr size_t WPROJT_SZ= (size_t)D_ * D_ * 2;
    constexpr size_t HEAD_SZ  = (size_t)B_ * H_ * N_ * 64 * 2;

    _Float16* xn_p   = (_Float16*)(ws);                      // packed LN(x); reused as ao_p
    _Float16* wqkv_p = (_Float16*)(ws + XN_SZ);
    _Float16* wproj_p= (_Float16*)(ws + XN_SZ + WQKVT_SZ);
    _Float16* qb     = (_Float16*)(ws + XN_SZ + WQKVT_SZ + WPROJT_SZ);
    _Float16* kb     = (_Float16*)((char*)qb + HEAD_SZ);     // K fragment-major
    _Float16* vtb    = (_Float16*)((char*)kb + HEAD_SZ);     // V fragment-major
    _Float16* ao_p   = xn_p;                                 // xn dead after gemm_qkv

    convert_w<<<576, 256, 0, stream>>>(W_qkv, W_proj, wqkv_p, wproj_p);
    ln_embed<<<M_, 256, 0, stream>>>(x, ln_g, ln_b, xn_p);
    gemm_qkv<<<(M_ / 256) * (QKVN_ / 128), 256, 0, stream>>>(xn_p, wqkv_p, b_qkv,
                                                             qn_g, qn_b, kn_g, kn_b,
                                                             qb, kb, vtb);
    attn<<<B_ * H_ * (N_ / 128), 128, 0, stream>>>(qb, kb, vtb, ao_p);
    gemm_proj<<<(M_ / 256) * (D_ / 128), 256, 0, stream>>>(ao_p, wproj_p, b_proj, out);
}

// Round 10
// 207.984 us; speedup vs baseline: 1.0754x; 1.0754x over previous
//
#include <hip/hip_runtime.h>

typedef _Float16 half8 __attribute__((ext_vector_type(8)));
typedef _Float16 half4 __attribute__((ext_vector_type(4)));
typedef _Float16 half2v __attribute__((ext_vector_type(2)));
typedef float f32x4 __attribute__((ext_vector_type(4)));

#define B_    16
#define N_    1024
#define D_    768
#define H_    12
#define M_    (B_ * N_)     // 16384
#define QKVN_ 2304
#define EPS_  1e-5f
#define QS_   0.18033688011112042f   // 0.125 * log2(e)

__device__ __forceinline__ float exp2_fast(float x) {
#if __has_builtin(__builtin_amdgcn_exp2f)
    return __builtin_amdgcn_exp2f(x);
#else
    return __builtin_exp2f(x);
#endif
}

__device__ __forceinline__ void gl16(const _Float16* g, _Float16* l) {
    __builtin_amdgcn_global_load_lds((const __attribute__((address_space(1))) void*)g,
                                     (__attribute__((address_space(3))) void*)l, 16, 0, 0);
}

#define BARR() asm volatile("s_barrier" ::: "memory")
#define VM6()  asm volatile("s_waitcnt vmcnt(6)" ::: "memory")

// ---- A image (16384 x 768): per (mt=row>>8, kt=k>>6) 16384-half tile:
//      [(t16=(row>>4)&15)*2 + ksub=(k>>5)&1][lg=(k>>3)&3][p=row&15][e=k&7]
__device__ __forceinline__ size_t aidx(int row, int d) {
    return ((size_t)((row >> 8) * 12 + (d >> 6))) * 16384
         + ((((row >> 4) & 15) * 2) + ((d >> 5) & 1)) * 512
         + (((d >> 3) & 3)) * 128 + (row & 15) * 8 + (d & 7);
}
// ---- B image (cols x 768): per (nt=n>>7, kt) 8192-half tile:
//      [(t16=(n>>4)&7)*2 + ksub][lg][p=n&15][e]

// ---------------- weight cast + B-image pack (LDS-tiled transpose) ----------------
__global__ __launch_bounds__(256) void convert_w(const float* __restrict__ Wqkv,
                                                 const float* __restrict__ Wproj,
                                                 _Float16* __restrict__ wqkv_p,
                                                 _Float16* __restrict__ wproj_p) {
    __shared__ float T[64][65];                 // T[n_local][k_local]
    int t = blockIdx.x;
    const float* W; _Float16* O; int NW, k0, n0;
    if (t < 432) { W = Wqkv;  O = wqkv_p;  NW = QKVN_; k0 = (t % 12) * 64; n0 = (t / 12) * 64; }
    else { t -= 432; W = Wproj; O = wproj_p; NW = D_;  k0 = (t % 12) * 64; n0 = (t / 12) * 64; }
    int c = threadIdx.x & 63, r4 = threadIdx.x >> 6;
#pragma unroll
    for (int i = 0; i < 16; ++i) {
        int k = i * 4 + r4;
        T[c][k] = W[(size_t)(k0 + k) * NW + n0 + c];
    }
    __syncthreads();
    int kt = k0 >> 6;
    int ntile = n0 >> 7;
    int t16base = (n0 >> 4) & 7;
#pragma unroll
    for (int it = 0; it < 2; ++it) {
        int g = it * 256 + threadIdx.x;         // 0..511
        int t16l = g >> 7, ksub = (g >> 6) & 1, lgI = (g >> 4) & 3, p = g & 15;
        half8 v;
#pragma unroll
        for (int e = 0; e < 8; ++e)
            v[e] = (_Float16)T[t16l * 16 + p][ksub * 32 + lgI * 8 + e];
        *(half8*)&O[((size_t)(ntile * 12 + kt)) * 8192 +
                    ((t16base + t16l) * 2 + ksub) * 512 + lgI * 128 + p * 8] = v;
    }
}

// ---------------- embed LayerNorm -> xn in A image ----------------
__global__ __launch_bounds__(256) void ln_embed(const float* __restrict__ x,
                                                const float* __restrict__ g,
                                                const float* __restrict__ bb,
                                                _Float16* __restrict__ xp) {
    int row = blockIdx.x;
    int tid = threadIdx.x;
    const float2* xr = (const float2*)(x + (size_t)row * D_);
    float2 v0 = xr[tid];
    float2 v1 = make_float2(0.f, 0.f);
    if (tid < 128) v1 = xr[256 + tid];
    float s = v0.x + v0.y + v1.x + v1.y;
    float q = v0.x * v0.x + v0.y * v0.y + v1.x * v1.x + v1.y * v1.y;
#pragma unroll
    for (int m = 32; m >= 1; m >>= 1) {
        s += __shfl_xor(s, m);
        q += __shfl_xor(q, m);
    }
    __shared__ float ss[4], qq[4];
    int wave = tid >> 6;
    if ((tid & 63) == 0) { ss[wave] = s; qq[wave] = q; }
    __syncthreads();
    float S = ss[0] + ss[1] + ss[2] + ss[3];
    float Q = qq[0] + qq[1] + qq[2] + qq[3];
    float mean = S * (1.f / 768.f);
    float var  = Q * (1.f / 768.f) - mean * mean;
    float rstd = rsqrtf(var + EPS_);
    const float2* g2 = (const float2*)g;
    const float2* b2 = (const float2*)bb;
    {
        int d0 = 2 * tid;
        float2 ga = g2[tid], ba = b2[tid];
        half2v w;
        w[0] = (_Float16)((v0.x - mean) * rstd * ga.x + ba.x);
        w[1] = (_Float16)((v0.y - mean) * rstd * ga.y + ba.y);
        *(half2v*)&xp[aidx(row, d0)] = w;
    }
    if (tid < 128) {
        int d0 = 512 + 2 * tid;
        float2 ga = g2[256 + tid], ba = b2[256 + tid];
        half2v w;
        w[0] = (_Float16)((v1.x - mean) * rstd * ga.x + ba.x);
        w[1] = (_Float16)((v1.y - mean) * rstd * ga.y + ba.y);
        *(half2v*)&xp[aidx(row, d0)] = w;
    }
}

// ---------------- QKV GEMM: 256x128, 8 waves, ring-3 LDS, phase schedule ----------------
// Per K-tile(64): 2 phases {8 ds_read || 3 gl16 -> barrier -> setprio MFMA x16 -> barrier},
// ONE vmcnt(6) per tile (never 0); wrap-staged tail keeps counts uniform.
__global__ __launch_bounds__(512, 2) void gemm_qkv(const _Float16* __restrict__ Ap,
                                                   const _Float16* __restrict__ Bp,
                                                   const float* __restrict__ bias,
                                                   const float* __restrict__ qn_g,
                                                   const float* __restrict__ qn_b,
                                                   const float* __restrict__ kn_g,
                                                   const float* __restrict__ kn_b,
                                                   _Float16* __restrict__ qo,
                                                   _Float16* __restrict__ ko,
                                                   _Float16* __restrict__ vt) {
    __shared__ _Float16 lds[3 * 24576];                 // 144 KB: 3 x (A 32KB + B 16KB)
    int xcd = blockIdx.x & 7, loc = blockIdx.x >> 3;    // 1152 = 8 XCD * (8m * 18n)
    int mt = xcd * 8 + (loc & 7);                       // m fastest within XCD
    int nb = loc >> 3;                                  // 0..17
    int tid = threadIdx.x;
    int wid = tid >> 6, lane = tid & 63;
    int wm = wid >> 1, wn = wid & 1;
    int lg = lane >> 4, l15 = lane & 15;

    const _Float16* Abase = Ap + (size_t)mt * (12 * 16384) + wid * 512 + lane * 8;
    const _Float16* Bbase = Bp + (size_t)nb * (12 * 8192) + wid * 512 + lane * 8;

    f32x4 acc[4][4] = {};
    half8 a[4], b[4];

#define STG_A(buf, kt, pass) gl16(Abase + (kt) * 16384 + (pass) * 4096, \
                                  &lds[(buf) * 24576 + (pass) * 4096 + wid * 512])
#define STG_B(buf, kt, pass) gl16(Bbase + (kt) * 8192 + (pass) * 4096, \
                                  &lds[(buf) * 24576 + 16384 + (pass) * 4096 + wid * 512])
#define DSRD(buf, ks)                                                                 \
    _Pragma("unroll")                                                                 \
    for (int mi = 0; mi < 4; ++mi)                                                    \
        a[mi] = *(const half8*)&lds[(buf) * 24576 + ((wm * 4 + mi) * 2 + (ks)) * 512 + lane * 8]; \
    _Pragma("unroll")                                                                 \
    for (int ni = 0; ni < 4; ++ni)                                                    \
        b[ni] = *(const half8*)&lds[(buf) * 24576 + 16384 + ((wn * 4 + ni) * 2 + (ks)) * 512 + lane * 8];
#define MM16()                                                                        \
    _Pragma("unroll")                                                                 \
    for (int mi = 0; mi < 4; ++mi)                                                    \
        _Pragma("unroll")                                                             \
        for (int ni = 0; ni < 4; ++ni)                                                \
            acc[mi][ni] = __builtin_amdgcn_mfma_f32_16x16x32_f16(a[mi], b[ni], acc[mi][ni], 0, 0, 0);

    // prologue: tiles 0,1 (6 gl16 each)
#pragma unroll
    for (int u = 0; u < 2; ++u) {
        STG_A(u, u, 0); STG_A(u, u, 1); STG_B(u, u, 0);
        STG_A(u, u, 2); STG_A(u, u, 3); STG_B(u, u, 1);
    }
    VM6();          // tile0 landed
    BARR();

    for (int t = 0; t < 12; ++t) {
        int buf = t % 3;
        int nbuf = (t + 2) % 3;
        int ktw = (t >= 10) ? (t - 10) : (t + 2);       // wrap: redundant but uniform
        // phase 0 (ksub=0)
        DSRD(buf, 0);
        STG_A(nbuf, ktw, 0); STG_A(nbuf, ktw, 1); STG_B(nbuf, ktw, 0);
        BARR();
        __builtin_amdgcn_s_setprio(1);
        MM16();
        __builtin_amdgcn_s_setprio(0);
        BARR();
        // phase 1 (ksub=1)
        DSRD(buf, 1);
        STG_A(nbuf, ktw, 2); STG_A(nbuf, ktw, 3); STG_B(nbuf, ktw, 1);
        VM6();      // tile t+1 fully landed before its reads next iter
        BARR();
        __builtin_amdgcn_s_setprio(1);
        MM16();
        __builtin_amdgcn_s_setprio(0);
        BARR();
    }
#undef STG_A
#undef STG_B
#undef DSRD
#undef MM16

    // ---- epilogue: fused per-head LN + fragment-major scatter ----
    int m0 = mt * 256, n0 = nb * 128;
    int col0 = n0 + wn * 64;
    int s = col0 / 768;
    int hcol = (col0 % 768) >> 6;
    float qkvb[4];
#pragma unroll
    for (int ni = 0; ni < 4; ++ni) qkvb[ni] = bias[col0 + ni * 16 + l15];

    if (s == 2) {
#pragma unroll
        for (int mi = 0; mi < 4; ++mi) {
            int r0 = m0 + wm * 64 + mi * 16 + lg * 4;
            int bidx = r0 >> 10, pos = r0 & 1023;
            int kvblk = pos >> 5, h = (pos >> 4) & 1, lgR = (pos >> 2) & 3;
            size_t vbase = ((size_t)(bidx * H_ + hcol) * 32 + kvblk) * 4;
#pragma unroll
            for (int ni = 0; ni < 4; ++ni) {
                half4 h4;
#pragma unroll
                for (int j = 0; j < 4; ++j) h4[j] = (_Float16)(acc[mi][ni][j] + qkvb[ni]);
                *(half4*)&vt[(vbase + ni) * 512 + lgR * 128 + l15 * 8 + h * 4] = h4;
            }
        }
    } else {
        const float* gg = (s == 0) ? qn_g : kn_g;
        const float* bb = (s == 0) ? qn_b : kn_b;
        float gv[4], bv[4];
#pragma unroll
        for (int ni = 0; ni < 4; ++ni) { gv[ni] = gg[ni * 16 + l15]; bv[ni] = bb[ni * 16 + l15]; }
#pragma unroll
        for (int mi = 0; mi < 4; ++mi) {
#pragma unroll
            for (int j = 0; j < 4; ++j) {
                float v[4];
                float sm = 0.f, sq = 0.f;
#pragma unroll
                for (int ni = 0; ni < 4; ++ni) {
                    v[ni] = acc[mi][ni][j] + qkvb[ni];
                    sm += v[ni];
                    sq += v[ni] * v[ni];
                }
#pragma unroll
                for (int msk = 1; msk < 16; msk <<= 1) {
                    sm += __shfl_xor(sm, msk);
                    sq += __shfl_xor(sq, msk);
                }
                float mean = sm * (1.f / 64.f);
                float var  = sq * (1.f / 64.f) - mean * mean;
                float rstd = rsqrtf(var + EPS_);
                int row = m0 + wm * 64 + mi * 16 + lg * 4 + j;
                int bidx = row >> 10, pos = row & 1023;
                if (s == 0) {
                    size_t rbase = ((size_t)(bidx * H_ + hcol) * 1024 + pos) * 64;
#pragma unroll
                    for (int ni = 0; ni < 4; ++ni) {
                        float o = (v[ni] - mean) * rstd * gv[ni] + bv[ni];
                        qo[rbase + ni * 16 + l15] = (_Float16)(o * QS_);
                    }
                } else {
                    int kvblk = pos >> 5, nh = (pos >> 4) & 1, l15R = pos & 15;
                    size_t base2 = ((size_t)(bidx * H_ + hcol) * 32 + kvblk) * 4 + nh * 2;
#pragma unroll
                    for (int ni = 0; ni < 4; ++ni) {
                        float o = (v[ni] - mean) * rstd * gv[ni] + bv[ni];
                        int ks = ni >> 1, lgR = ((ni & 1) << 1) | (l15 >> 3), elem = l15 & 7;
                        ko[(base2 + ks) * 512 + lgR * 128 + l15R * 8 + elem] = (_Float16)o;
                    }
                }
            }
        }
    }
}

// ---------------- flash attention: pure-register; output -> proj A image ----------
struct KV {
    half8 kf[2][2];
    half8 vf[4];
};

__device__ __forceinline__ void ldKV(KV& s, const _Float16* kp, const _Float16* vp, int kvblk) {
    const _Float16* kb = kp + (size_t)kvblk * 2048;
#pragma unroll
    for (int nh = 0; nh < 2; ++nh)
#pragma unroll
        for (int ks = 0; ks < 2; ++ks)
            s.kf[nh][ks] = *(const half8*)(kb + (nh * 2 + ks) * 512);
    const _Float16* vb = vp + (size_t)kvblk * 2048;
#pragma unroll
    for (int di = 0; di < 4; ++di)
        s.vf[di] = *(const half8*)(vb + di * 512);
}

__device__ __forceinline__ void blockKV(const KV& s, const half8 (&qf)[4][2],
                                        f32x4 (&oacc)[4][4], f32x4 (&lacc)[4],
                                        half8 ones) {
#pragma unroll
    for (int mi = 0; mi < 4; ++mi) {
        f32x4 a0 = {}, a1 = {};
#pragma unroll
        for (int ks = 0; ks < 2; ++ks) {
            a0 = __builtin_amdgcn_mfma_f32_16x16x32_f16(s.kf[0][ks], qf[mi][ks], a0, 0, 0, 0);
            a1 = __builtin_amdgcn_mfma_f32_16x16x32_f16(s.kf[1][ks], qf[mi][ks], a1, 0, 0, 0);
        }
        half8 pf;
#pragma unroll
        for (int j = 0; j < 4; ++j) {
            pf[j]     = (_Float16)exp2_fast(a0[j]);
            pf[j + 4] = (_Float16)exp2_fast(a1[j]);
        }
        lacc[mi] = __builtin_amdgcn_mfma_f32_16x16x32_f16(ones, pf, lacc[mi], 0, 0, 0);
#pragma unroll
        for (int di = 0; di < 4; ++di)
            oacc[mi][di] = __builtin_amdgcn_mfma_f32_16x16x32_f16(s.vf[di], pf, oacc[mi][di], 0, 0, 0);
    }
}

__global__ __launch_bounds__(128, 2) void attn(const _Float16* __restrict__ qg,
                                               const _Float16* __restrict__ kg,
                                               const _Float16* __restrict__ vtg,
                                               _Float16* __restrict__ op) {
    int bphys = blockIdx.x;
    int jj = (bphys & 7) * 192 + (bphys >> 3);
    int bh = jj >> 3, qt = jj & 7;
    int b = bh / H_, h = bh % H_;
    int tid = threadIdx.x;
    int wid = tid >> 6, lane = tid & 63;
    int lg = lane >> 4, l15 = lane & 15;
    size_t base = (size_t)bh << 10;
    int qw0 = qt * 128 + wid * 64;

    const _Float16* qrow = qg + (base + qw0 + l15) * 64 + lg * 8;
    half8 qf[4][2];
#pragma unroll
    for (int mi = 0; mi < 4; ++mi)
#pragma unroll
        for (int ks = 0; ks < 2; ++ks)
            qf[mi][ks] = *(const half8*)(qrow + mi * 1024 + ks * 32);

    const _Float16* kp = kg + (size_t)bh * 65536 + lane * 8;
    const _Float16* vp = vtg + (size_t)bh * 65536 + lane * 8;

    half8 ones;
#pragma unroll
    for (int i = 0; i < 8; ++i) ones[i] = (_Float16)1.0f;

    f32x4 oacc[4][4] = {};
    f32x4 lacc[4] = {};

    KV s0, s1;
    ldKV(s0, kp, vp, 0);
    for (int t = 0; t < 16; ++t) {
        ldKV(s1, kp, vp, (2 * t + 1) & 31);
        blockKV(s0, qf, oacc, lacc, ones);
        ldKV(s0, kp, vp, (2 * t + 2) & 31);
        blockKV(s1, qf, oacc, lacc, ones);
    }

    // write O into proj A image: row = b*1024 + qw0 + mi*16 + l15, k = 64h + 16di + 4lg + j
#pragma unroll
    for (int mi = 0; mi < 4; ++mi) {
        float inv = 1.f / lacc[mi][0];
        int row0 = b * 1024 + qw0 + mi * 16;
        int mtv = row0 >> 8, t16 = (row0 >> 4) & 15;
#pragma unroll
        for (int di = 0; di < 4; ++di) {
            half4 h4;
#pragma unroll
            for (int j = 0; j < 4; ++j) h4[j] = (_Float16)(oacc[mi][di][j] * inv);
            size_t o = ((size_t)(mtv * 12 + h)) * 16384 + (t16 * 2 + (di >> 1)) * 512
                     + ((di & 1) * 2 + (lg >> 1)) * 128 + l15 * 8 + (lg & 1) * 4;
            *(half4*)&op[o] = h4;
        }
    }
}

// ---------------- proj GEMM: same phase-template structure, fp32 epilogue ----------------
__global__ __launch_bounds__(512, 2) void gemm_proj(const _Float16* __restrict__ Ap,
                                                    const _Float16* __restrict__ Bp,
                                                    const float* __restrict__ bias,
                                                    float* __restrict__ out) {
    __shared__ _Float16 lds[3 * 24576];
    int xcd = blockIdx.x & 7, loc = blockIdx.x >> 3;    // 384 = 8 XCD * (8m * 6n)
    int mt = xcd * 8 + (loc & 7);
    int nb = loc >> 3;                                  // 0..5
    int tid = threadIdx.x;
    int wid = tid >> 6, lane = tid & 63;
    int wm = wid >> 1, wn = wid & 1;
    int lg = lane >> 4, l15 = lane & 15;

    const _Float16* Abase = Ap + (size_t)mt * (12 * 16384) + wid * 512 + lane * 8;
    const _Float16* Bbase = Bp + (size_t)nb * (12 * 8192) + wid * 512 + lane * 8;

    f32x4 acc[4][4] = {};
    half8 a[4], b[4];

#define STG_A(buf, kt, pass) gl16(Abase + (kt) * 16384 + (pass) * 4096, \
                                  &lds[(buf) * 24576 + (pass) * 4096 + wid * 512])
#define STG_B(buf, kt, pass) gl16(Bbase + (kt) * 8192 + (pass) * 4096, \
                                  &lds[(buf) * 24576 + 16384 + (pass) * 4096 + wid * 512])
#define DSRD(buf, ks)                                                                 \
    _Pragma("unroll")                                                                 \
    for (int mi = 0; mi < 4; ++mi)                                                    \
        a[mi] = *(const half8*)&lds[(buf) * 24576 + ((wm * 4 + mi) * 2 + (ks)) * 512 + lane * 8]; \
    _Pragma("unroll")                                                                 \
    for (int ni = 0; ni < 4; ++ni)                                                    \
        b[ni] = *(const half8*)&lds[(buf) * 24576 + 16384 + ((wn * 4 + ni) * 2 + (ks)) * 512 + lane * 8];
#define MM16()                                                                        \
    _Pragma("unroll")                                                                 \
    for (int mi = 0; mi < 4; ++mi)                                                    \
        _Pragma("unroll")                                                             \
        for (int ni = 0; ni < 4; ++ni)                                                \
            acc[mi][ni] = __builtin_amdgcn_mfma_f32_16x16x32_f16(a[mi], b[ni], acc[mi][ni], 0, 0, 0);

#pragma unroll
    for (int u = 0; u < 2; ++u) {
        STG_A(u, u, 0); STG_A(u, u, 1); STG_B(u, u, 0);
        STG_A(u, u, 2); STG_A(u, u, 3); STG_B(u, u, 1);
    }
    VM6();
    BARR();

    for (int t = 0; t < 12; ++t) {
        int buf = t % 3;
        int nbuf = (t + 2) % 3;
        int ktw = (t >= 10) ? (t - 10) : (t + 2);
        DSRD(buf, 0);
        STG_A(nbuf, ktw, 0); STG_A(nbuf, ktw, 1); STG_B(nbuf, ktw, 0);
        BARR();
        __builtin_amdgcn_s_setprio(1);
        MM16();
        __builtin_amdgcn_s_setprio(0);
        BARR();
        DSRD(buf, 1);
        STG_A(nbuf, ktw, 2); STG_A(nbuf, ktw, 3); STG_B(nbuf, ktw, 1);
        VM6();
        BARR();
        __builtin_amdgcn_s_setprio(1);
        MM16();
        __builtin_amdgcn_s_setprio(0);
        BARR();
    }
#undef STG_A
#undef STG_B
#undef DSRD
#undef MM16

    int m0 = mt * 256, n0 = nb * 128;
#pragma unroll
    for (int mi = 0; mi < 4; ++mi)
#pragma unroll
        for (int ni = 0; ni < 4; ++ni) {
            int col = n0 + wn * 64 + ni * 16 + l15;
            float bv = bias[col];
#pragma unroll
            for (int j = 0; j < 4; ++j) {
                int row = m0 + wm * 64 + mi * 16 + lg * 4 + j;
                out[(size_t)row * D_ + col] = acc[mi][ni][j] + bv;
            }
        }
}

// ---------------- launch ----------------
extern "C" void kernel_launch(void* const* d_in, const int* in_sizes, int n_in,
                              void* d_out, int out_size, void* d_ws, size_t ws_size,
                              hipStream_t stream) {
    const float* x      = (const float*)d_in[0];
    const float* ln_g   = (const float*)d_in[1];
    const float* ln_b   = (const float*)d_in[2];
    const float* W_qkv  = (const float*)d_in[3];
    const float* b_qkv  = (const float*)d_in[4];
    const float* qn_g   = (const float*)d_in[5];
    const float* qn_b   = (const float*)d_in[6];
    const float* kn_g   = (const float*)d_in[7];
    const float* kn_b   = (const float*)d_in[8];
    const float* W_proj = (const float*)d_in[9];
    const float* b_proj = (const float*)d_in[10];
    float* out = (float*)d_out;
    char* ws = (char*)d_ws;

    constexpr size_t XN_SZ    = (size_t)M_ * D_ * 2;
    constexpr size_t WQKVT_SZ = (size_t)QKVN_ * D_ * 2;
    constexpr size_t WPROJT_SZ= (size_t)D_ * D_ * 2;
    constexpr size_t HEAD_SZ  = (size_t)B_ * H_ * N_ * 64 * 2;

    _Float16* xn_p   = (_Float16*)(ws);                      // A image; reused as proj-A image
    _Float16* wqkv_p = (_Float16*)(ws + XN_SZ);              // B image (2304 cols)
    _Float16* wproj_p= (_Float16*)(ws + XN_SZ + WQKVT_SZ);   // B image (768 cols)
    _Float16* qb     = (_Float16*)(ws + XN_SZ + WQKVT_SZ + WPROJT_SZ);
    _Float16* kb     = (_Float16*)((char*)qb + HEAD_SZ);     // K fragment-major
    _Float16* vtb    = (_Float16*)((char*)kb + HEAD_SZ);     // V fragment-major
    _Float16* ao_p   = xn_p;                                 // xn dead after gemm_qkv

    convert_w<<<576, 256, 0, stream>>>(W_qkv, W_proj, wqkv_p, wproj_p);
    ln_embed<<<M_, 256, 0, stream>>>(x, ln_g, ln_b, xn_p);
    gemm_qkv<<<(M_ / 256) * (QKVN_ / 128), 512, 0, stream>>>(xn_p, wqkv_p, b_qkv,
                                                             qn_g, qn_b, kn_g, kn_b,
                                                             qb, kb, vtb);
    attn<<<B_ * H_ * (N_ / 128), 128, 0, stream>>>(qb, kb, vtb, ao_p);
    gemm_proj<<<(M_ / 256) * (D_ / 128), 512, 0, stream>>>(ao_p, wproj_p, b_proj, out);
}

// Round 11
// 190.126 us; speedup vs baseline: 1.1764x; 1.0939x over previous
//
#include <hip/hip_runtime.h>

typedef _Float16 half8 __attribute__((ext_vector_type(8)));
typedef _Float16 half4 __attribute__((ext_vector_type(4)));
typedef _Float16 half2v __attribute__((ext_vector_type(2)));
typedef float f32x4 __attribute__((ext_vector_type(4)));

#define B_    16
#define N_    1024
#define D_    768
#define H_    12
#define M_    (B_ * N_)     // 16384
#define QKVN_ 2304
#define EPS_  1e-5f
#define QS_   0.18033688011112042f   // 0.125 * log2(e)

__device__ __forceinline__ float exp2_fast(float x) {
#if __has_builtin(__builtin_amdgcn_exp2f)
    return __builtin_amdgcn_exp2f(x);
#else
    return __builtin_exp2f(x);
#endif
}

// ---- A image (rows x 768): per (mt=row>>8, kt=k>>6) 16384-half tile:
//      [(t16=(row>>4)&15)*2 + ksub=(k>>5)&1][lg=(k>>3)&3][p=row&15][e=k&7]
__device__ __forceinline__ size_t aidx(int row, int d) {
    return ((size_t)((row >> 8) * 12 + (d >> 6))) * 16384
         + ((((row >> 4) & 15) * 2) + ((d >> 5) & 1)) * 512
         + (((d >> 3) & 3)) * 128 + (row & 15) * 8 + (d & 7);
}
// ---- B image (cols x 768): per (nt=n>>7, kt) 8192-half tile: [(t16=(n>>4)&7)*2+ksub][lg][p][e]

// ---------------- weight cast + B-image pack ----------------
__global__ __launch_bounds__(256) void convert_w(const float* __restrict__ Wqkv,
                                                 const float* __restrict__ Wproj,
                                                 _Float16* __restrict__ wqkv_p,
                                                 _Float16* __restrict__ wproj_p) {
    __shared__ float T[64][65];
    int t = blockIdx.x;
    const float* W; _Float16* O; int NW, k0, n0;
    if (t < 432) { W = Wqkv;  O = wqkv_p;  NW = QKVN_; k0 = (t % 12) * 64; n0 = (t / 12) * 64; }
    else { t -= 432; W = Wproj; O = wproj_p; NW = D_;  k0 = (t % 12) * 64; n0 = (t / 12) * 64; }
    int c = threadIdx.x & 63, r4 = threadIdx.x >> 6;
#pragma unroll
    for (int i = 0; i < 16; ++i) {
        int k = i * 4 + r4;
        T[c][k] = W[(size_t)(k0 + k) * NW + n0 + c];
    }
    __syncthreads();
    int kt = k0 >> 6;
    int ntile = n0 >> 7;
    int t16base = (n0 >> 4) & 7;
#pragma unroll
    for (int it = 0; it < 2; ++it) {
        int g = it * 256 + threadIdx.x;
        int t16l = g >> 7, ksub = (g >> 6) & 1, lgI = (g >> 4) & 3, p = g & 15;
        half8 v;
#pragma unroll
        for (int e = 0; e < 8; ++e)
            v[e] = (_Float16)T[t16l * 16 + p][ksub * 32 + lgI * 8 + e];
        *(half8*)&O[((size_t)(ntile * 12 + kt)) * 8192 +
                    ((t16base + t16l) * 2 + ksub) * 512 + lgI * 128 + p * 8] = v;
    }
}

// ---------------- embed LayerNorm -> xn in A image ----------------
__global__ __launch_bounds__(256) void ln_embed(const float* __restrict__ x,
                                                const float* __restrict__ g,
                                                const float* __restrict__ bb,
                                                _Float16* __restrict__ xp) {
    int row = blockIdx.x;
    int tid = threadIdx.x;
    const float2* xr = (const float2*)(x + (size_t)row * D_);
    float2 v0 = xr[tid];
    float2 v1 = make_float2(0.f, 0.f);
    if (tid < 128) v1 = xr[256 + tid];
    float s = v0.x + v0.y + v1.x + v1.y;
    float q = v0.x * v0.x + v0.y * v0.y + v1.x * v1.x + v1.y * v1.y;
#pragma unroll
    for (int m = 32; m >= 1; m >>= 1) {
        s += __shfl_xor(s, m);
        q += __shfl_xor(q, m);
    }
    __shared__ float ss[4], qq[4];
    int wave = tid >> 6;
    if ((tid & 63) == 0) { ss[wave] = s; qq[wave] = q; }
    __syncthreads();
    float S = ss[0] + ss[1] + ss[2] + ss[3];
    float Q = qq[0] + qq[1] + qq[2] + qq[3];
    float mean = S * (1.f / 768.f);
    float var  = Q * (1.f / 768.f) - mean * mean;
    float rstd = rsqrtf(var + EPS_);
    const float2* g2 = (const float2*)g;
    const float2* b2 = (const float2*)bb;
    {
        int d0 = 2 * tid;
        float2 ga = g2[tid], ba = b2[tid];
        half2v w;
        w[0] = (_Float16)((v0.x - mean) * rstd * ga.x + ba.x);
        w[1] = (_Float16)((v0.y - mean) * rstd * ga.y + ba.y);
        *(half2v*)&xp[aidx(row, d0)] = w;
    }
    if (tid < 128) {
        int d0 = 512 + 2 * tid;
        float2 ga = g2[256 + tid], ba = b2[256 + tid];
        half2v w;
        w[0] = (_Float16)((v1.x - mean) * rstd * ga.x + ba.x);
        w[1] = (_Float16)((v1.y - mean) * rstd * ga.y + ba.y);
        *(half2v*)&xp[aidx(row, d0)] = w;
    }
}

// ---------------- QKV GEMM: pure-register (R6 main loop), dual-orientation epilogue ------
// Q/K blocks compute the TRANSPOSED product mfma(W,X): acc col = pos, regs = d.
// -> LN reduce = local16 + 2 shfl; Q/K pack stores are half4-contiguous.
// V blocks keep normal orientation (half4 kv-stores). Same 8 loads either way.
__global__ __launch_bounds__(256, 3) void gemm_qkv(const _Float16* __restrict__ Xp,
                                                   const _Float16* __restrict__ Wp,
                                                   const float* __restrict__ bias,
                                                   const float* __restrict__ qn_g,
                                                   const float* __restrict__ qn_b,
                                                   const float* __restrict__ kn_g,
                                                   const float* __restrict__ kn_b,
                                                   _Float16* __restrict__ qo,
                                                   _Float16* __restrict__ ko,
                                                   _Float16* __restrict__ vt) {
    int xcd = blockIdx.x & 7, loc = blockIdx.x >> 3;     // 2304 = 8 XCD * (16 m * 18 n)
    int mblk = xcd * 16 + (loc & 15);                    // m fastest within XCD
    int nb = loc >> 4;                                   // 0..17
    int tid = threadIdx.x;
    int wid = tid >> 6, lane = tid & 63;
    int wm = wid >> 1, wn = wid & 1;
    int lg = lane >> 4, l15 = lane & 15;
    bool isV = (nb >= 12);

    const _Float16* pw = Wp + (size_t)nb * 98304 + (wn * 4) * 1024 + lane * 8;
    const _Float16* px = Xp + (size_t)(mblk >> 1) * 196608 +
                         ((mblk & 1) * 8 + wm * 4) * 1024 + lane * 8;

    f32x4 acc[4][4] = {};
    half8 xa0[4], wb0[4], xa1[4], wb1[4];
    auto ld = [&](half8 (&xa)[4], half8 (&wb)[4], int t) {
        int kt = t >> 1, ks = t & 1;
        size_t offW = (size_t)kt * 8192 + ks * 512;
        size_t offX = (size_t)kt * 16384 + ks * 512;
#pragma unroll
        for (int i = 0; i < 4; ++i) {
            xa[i] = *(const half8*)(px + i * 1024 + offX);
            wb[i] = *(const half8*)(pw + i * 1024 + offW);
        }
    };
    auto mmQK = [&](half8 (&xa)[4], half8 (&wb)[4]) {    // acc[ni][mi] = W x X^T
#pragma unroll
        for (int ni = 0; ni < 4; ++ni)
#pragma unroll
            for (int mi = 0; mi < 4; ++mi)
                acc[ni][mi] = __builtin_amdgcn_mfma_f32_16x16x32_f16(wb[ni], xa[mi], acc[ni][mi], 0, 0, 0);
    };
    auto mmV = [&](half8 (&xa)[4], half8 (&wb)[4]) {     // acc[mi][ni] = X x W^T
#pragma unroll
        for (int mi = 0; mi < 4; ++mi)
#pragma unroll
            for (int ni = 0; ni < 4; ++ni)
                acc[mi][ni] = __builtin_amdgcn_mfma_f32_16x16x32_f16(xa[mi], wb[ni], acc[mi][ni], 0, 0, 0);
    };

    ld(xa0, wb0, 0);
    if (isV) {
        for (int tt = 0; tt < 11; ++tt) {
            ld(xa1, wb1, 2 * tt + 1);
            mmV(xa0, wb0);
            ld(xa0, wb0, 2 * tt + 2);
            mmV(xa1, wb1);
        }
        ld(xa1, wb1, 23);
        mmV(xa0, wb0);
        mmV(xa1, wb1);
    } else {
        for (int tt = 0; tt < 11; ++tt) {
            ld(xa1, wb1, 2 * tt + 1);
            mmQK(xa0, wb0);
            ld(xa0, wb0, 2 * tt + 2);
            mmQK(xa1, wb1);
        }
        ld(xa1, wb1, 23);
        mmQK(xa0, wb0);
        mmQK(xa1, wb1);
    }

    int m0 = mblk * 128;
    int col0 = nb * 128 + wn * 64;

    if (isV) {
        // ---- V epilogue (normal orientation): half4 along kv into V-pack ----
        int hcol = (col0 % 768) >> 6;
        float qkvb[4];
#pragma unroll
        for (int ni = 0; ni < 4; ++ni) qkvb[ni] = bias[col0 + ni * 16 + l15];
#pragma unroll
        for (int mi = 0; mi < 4; ++mi) {
            int r0 = m0 + wm * 64 + mi * 16 + lg * 4;
            int bidx = r0 >> 10, pos = r0 & 1023;
            int kvblk = pos >> 5, h = (pos >> 4) & 1, lgR = (pos >> 2) & 3;
            size_t vbase = ((size_t)(bidx * H_ + hcol) * 32 + kvblk) * 4;
#pragma unroll
            for (int ni = 0; ni < 4; ++ni) {
                half4 h4;
#pragma unroll
                for (int j = 0; j < 4; ++j) h4[j] = (_Float16)(acc[mi][ni][j] + qkvb[ni]);
                *(half4*)&vt[(vbase + ni) * 512 + lgR * 128 + l15 * 8 + h * 4] = h4;
            }
        }
    } else {
        // ---- Q/K epilogue (swapped): lane col = pos, regs = d ----
        int s = col0 / 768;
        int hcol = (col0 % 768) >> 6;
        const float* gg = (s == 0) ? qn_g : kn_g;
        const float* bv = (s == 0) ? qn_b : kn_b;
        _Float16* dst = (s == 0) ? qo : ko;
        float4 g4[4], b4[4], bi4[4];
#pragma unroll
        for (int ni = 0; ni < 4; ++ni) {
            g4[ni]  = *(const float4*)&gg[ni * 16 + lg * 4];
            b4[ni]  = *(const float4*)&bv[ni * 16 + lg * 4];
            bi4[ni] = *(const float4*)&bias[col0 + ni * 16 + lg * 4];
        }
        int posbase = m0 + wm * 64;                       // 64-aligned; same batch for all 64
        int bidx = posbase >> 10;
        size_t bh0 = (size_t)(bidx * H_ + hcol) * 65536;
        float scl = (s == 0) ? QS_ : 1.0f;
#pragma unroll
        for (int mi = 0; mi < 4; ++mi) {
            float vv[4][4];
            float sm = 0.f, sq = 0.f;
#pragma unroll
            for (int ni = 0; ni < 4; ++ni)
#pragma unroll
                for (int j = 0; j < 4; ++j) {
                    float bvj = (j == 0) ? bi4[ni].x : (j == 1) ? bi4[ni].y : (j == 2) ? bi4[ni].z : bi4[ni].w;
                    float v = acc[ni][mi][j] + bvj;
                    vv[ni][j] = v;
                    sm += v;
                    sq += v * v;
                }
            sm += __shfl_xor(sm, 16); sq += __shfl_xor(sq, 16);
            sm += __shfl_xor(sm, 32); sq += __shfl_xor(sq, 32);
            float mean = sm * (1.f / 64.f);
            float var  = sq * (1.f / 64.f) - mean * mean;
            float rstd = rsqrtf(var + EPS_) * scl;
            float meanb = mean;
            int posL = ((posbase & 1023) + mi * 16);
            size_t obase = bh0 + (size_t)(posL >> 5) * 2048 + ((posL >> 4) & 1) * 1024
                         + l15 * 8 + (lg & 1) * 4;
#pragma unroll
            for (int ni = 0; ni < 4; ++ni) {
                half4 h4;
#pragma unroll
                for (int j = 0; j < 4; ++j) {
                    float gj = (j == 0) ? g4[ni].x : (j == 1) ? g4[ni].y : (j == 2) ? g4[ni].z : g4[ni].w;
                    float bj = (j == 0) ? b4[ni].x : (j == 1) ? b4[ni].y : (j == 2) ? b4[ni].z : b4[ni].w;
                    h4[j] = (_Float16)((vv[ni][j] - meanb) * rstd * gj + bj * scl);
                }
                dst[obase + (ni >> 1) * 512 + (((ni & 1) << 1) | (lg >> 1)) * 128] = h4[0];
                *(half4*)&dst[obase + (ni >> 1) * 512 + (((ni & 1) << 1) | (lg >> 1)) * 128] = h4;
            }
        }
    }
}

// ---------------- flash attention: pure-register; Q from pack; output -> proj A image ----
struct KV {
    half8 kf[2][2];
    half8 vf[4];
};

__device__ __forceinline__ void ldKV(KV& s, const _Float16* kp, const _Float16* vp, int kvblk) {
    const _Float16* kb = kp + (size_t)kvblk * 2048;
#pragma unroll
    for (int nh = 0; nh < 2; ++nh)
#pragma unroll
        for (int ks = 0; ks < 2; ++ks)
            s.kf[nh][ks] = *(const half8*)(kb + (nh * 2 + ks) * 512);
    const _Float16* vb = vp + (size_t)kvblk * 2048;
#pragma unroll
    for (int di = 0; di < 4; ++di)
        s.vf[di] = *(const half8*)(vb + di * 512);
}

__device__ __forceinline__ void blockKV(const KV& s, const half8 (&qf)[4][2],
                                        f32x4 (&oacc)[4][4], f32x4 (&lacc)[4],
                                        half8 ones) {
#pragma unroll
    for (int mi = 0; mi < 4; ++mi) {
        f32x4 a0 = {}, a1 = {};
#pragma unroll
        for (int ks = 0; ks < 2; ++ks) {
            a0 = __builtin_amdgcn_mfma_f32_16x16x32_f16(s.kf[0][ks], qf[mi][ks], a0, 0, 0, 0);
            a1 = __builtin_amdgcn_mfma_f32_16x16x32_f16(s.kf[1][ks], qf[mi][ks], a1, 0, 0, 0);
        }
        half8 pf;
#pragma unroll
        for (int j = 0; j < 4; ++j) {
            pf[j]     = (_Float16)exp2_fast(a0[j]);
            pf[j + 4] = (_Float16)exp2_fast(a1[j]);
        }
        lacc[mi] = __builtin_amdgcn_mfma_f32_16x16x32_f16(ones, pf, lacc[mi], 0, 0, 0);
#pragma unroll
        for (int di = 0; di < 4; ++di)
            oacc[mi][di] = __builtin_amdgcn_mfma_f32_16x16x32_f16(s.vf[di], pf, oacc[mi][di], 0, 0, 0);
    }
}

__global__ __launch_bounds__(128, 2) void attn(const _Float16* __restrict__ qg,
                                               const _Float16* __restrict__ kg,
                                               const _Float16* __restrict__ vtg,
                                               _Float16* __restrict__ op) {
    int bphys = blockIdx.x;
    int jj = (bphys & 7) * 192 + (bphys >> 3);
    int bh = jj >> 3, qt = jj & 7;
    int b = bh / H_, h = bh % H_;
    int tid = threadIdx.x;
    int wid = tid >> 6, lane = tid & 63;
    int lg = lane >> 4, l15 = lane & 15;
    int qw0 = qt * 128 + wid * 64;

    // Q from Q-pack: fully coalesced 1KB fragment reads
    const _Float16* qp2 = qg + (size_t)bh * 65536 + (size_t)(qw0 >> 5) * 2048 + lane * 8;
    half8 qf[4][2];
#pragma unroll
    for (int mi = 0; mi < 4; ++mi)
#pragma unroll
        for (int ks = 0; ks < 2; ++ks)
            qf[mi][ks] = *(const half8*)(qp2 + (mi >> 1) * 2048 + (mi & 1) * 1024 + ks * 512);

    const _Float16* kp = kg + (size_t)bh * 65536 + lane * 8;
    const _Float16* vp = vtg + (size_t)bh * 65536 + lane * 8;

    half8 ones;
#pragma unroll
    for (int i = 0; i < 8; ++i) ones[i] = (_Float16)1.0f;

    f32x4 oacc[4][4] = {};
    f32x4 lacc[4] = {};

    KV s0, s1;
    ldKV(s0, kp, vp, 0);
    for (int t = 0; t < 16; ++t) {
        ldKV(s1, kp, vp, (2 * t + 1) & 31);
        blockKV(s0, qf, oacc, lacc, ones);
        ldKV(s0, kp, vp, (2 * t + 2) & 31);
        blockKV(s1, qf, oacc, lacc, ones);
    }

    // write O into proj A image: row = b*1024 + qw0 + mi*16 + l15, k = 64h + 16di + 4lg + j
#pragma unroll
    for (int mi = 0; mi < 4; ++mi) {
        float inv = 1.f / lacc[mi][0];
        int row0 = b * 1024 + qw0 + mi * 16;
        int mtv = row0 >> 8, t16 = (row0 >> 4) & 15;
#pragma unroll
        for (int di = 0; di < 4; ++di) {
            half4 h4;
#pragma unroll
            for (int j = 0; j < 4; ++j) h4[j] = (_Float16)(oacc[mi][di][j] * inv);
            size_t o = ((size_t)(mtv * 12 + h)) * 16384 + (t16 * 2 + (di >> 1)) * 512
                     + ((di & 1) * 2 + (lg >> 1)) * 128 + l15 * 8 + (lg & 1) * 4;
            *(half4*)&op[o] = h4;
        }
    }
}

// ---------------- proj GEMM: pure-register from images (R6 structure) ----------------
__global__ __launch_bounds__(256, 3) void gemm_proj(const _Float16* __restrict__ Ap,
                                                    const _Float16* __restrict__ Wp,
                                                    const float* __restrict__ bias,
                                                    float* __restrict__ out) {
    int xcd = blockIdx.x & 7, loc = blockIdx.x >> 3;     // 768 = 8 XCD * (16 m * 6 n)
    int mblk = xcd * 16 + (loc & 15);
    int nb = loc >> 4;                                   // 0..5
    int tid = threadIdx.x;
    int wid = tid >> 6, lane = tid & 63;
    int wm = wid >> 1, wn = wid & 1;
    int lg = lane >> 4, l15 = lane & 15;

    const _Float16* pw = Wp + (size_t)nb * 98304 + (wn * 4) * 1024 + lane * 8;
    const _Float16* px = Ap + (size_t)(mblk >> 1) * 196608 +
                         ((mblk & 1) * 8 + wm * 4) * 1024 + lane * 8;

    f32x4 acc[4][4] = {};
    half8 xa0[4], wb0[4], xa1[4], wb1[4];
    auto ld = [&](half8 (&xa)[4], half8 (&wb)[4], int t) {
        int kt = t >> 1, ks = t & 1;
        size_t offW = (size_t)kt * 8192 + ks * 512;
        size_t offX = (size_t)kt * 16384 + ks * 512;
#pragma unroll
        for (int i = 0; i < 4; ++i) {
            xa[i] = *(const half8*)(px + i * 1024 + offX);
            wb[i] = *(const half8*)(pw + i * 1024 + offW);
        }
    };
    auto mm = [&](half8 (&xa)[4], half8 (&wb)[4]) {
#pragma unroll
        for (int mi = 0; mi < 4; ++mi)
#pragma unroll
            for (int ni = 0; ni < 4; ++ni)
                acc[mi][ni] = __builtin_amdgcn_mfma_f32_16x16x32_f16(xa[mi], wb[ni], acc[mi][ni], 0, 0, 0);
    };
    ld(xa0, wb0, 0);
    for (int tt = 0; tt < 11; ++tt) {
        ld(xa1, wb1, 2 * tt + 1);
        mm(xa0, wb0);
        ld(xa0, wb0, 2 * tt + 2);
        mm(xa1, wb1);
    }
    ld(xa1, wb1, 23);
    mm(xa0, wb0);
    mm(xa1, wb1);

    int m0 = mblk * 128, n0 = nb * 128;
#pragma unroll
    for (int mi = 0; mi < 4; ++mi)
#pragma unroll
        for (int ni = 0; ni < 4; ++ni) {
            int col = n0 + wn * 64 + ni * 16 + l15;
            float bv = bias[col];
#pragma unroll
            for (int j = 0; j < 4; ++j) {
                int row = m0 + wm * 64 + mi * 16 + lg * 4 + j;
                out[(size_t)row * D_ + col] = acc[mi][ni][j] + bv;
            }
        }
}

// ---------------- launch ----------------
extern "C" void kernel_launch(void* const* d_in, const int* in_sizes, int n_in,
                              void* d_out, int out_size, void* d_ws, size_t ws_size,
                              hipStream_t stream) {
    const float* x      = (const float*)d_in[0];
    const float* ln_g   = (const float*)d_in[1];
    const float* ln_b   = (const float*)d_in[2];
    const float* W_qkv  = (const float*)d_in[3];
    const float* b_qkv  = (const float*)d_in[4];
    const float* qn_g   = (const float*)d_in[5];
    const float* qn_b   = (const float*)d_in[6];
    const float* kn_g   = (const float*)d_in[7];
    const float* kn_b   = (const float*)d_in[8];
    const float* W_proj = (const float*)d_in[9];
    const float* b_proj = (const float*)d_in[10];
    float* out = (float*)d_out;
    char* ws = (char*)d_ws;

    constexpr size_t XN_SZ    = (size_t)M_ * D_ * 2;
    constexpr size_t WQKVT_SZ = (size_t)QKVN_ * D_ * 2;
    constexpr size_t WPROJT_SZ= (size_t)D_ * D_ * 2;
    constexpr size_t HEAD_SZ  = (size_t)B_ * H_ * N_ * 64 * 2;

    _Float16* xn_p   = (_Float16*)(ws);                      // A image; reused as proj-A image
    _Float16* wqkv_p = (_Float16*)(ws + XN_SZ);              // B image (2304 cols)
    _Float16* wproj_p= (_Float16*)(ws + XN_SZ + WQKVT_SZ);   // B image (768 cols)
    _Float16* qb     = (_Float16*)(ws + XN_SZ + WQKVT_SZ + WPROJT_SZ);  // Q pack
    _Float16* kb     = (_Float16*)((char*)qb + HEAD_SZ);     // K pack
    _Float16* vtb    = (_Float16*)((char*)kb + HEAD_SZ);     // V pack
    _Float16* ao_p   = xn_p;                                 // xn dead after gemm_qkv

    convert_w<<<576, 256, 0, stream>>>(W_qkv, W_proj, wqkv_p, wproj_p);
    ln_embed<<<M_, 256, 0, stream>>>(x, ln_g, ln_b, xn_p);
    gemm_qkv<<<(M_ / 128) * (QKVN_ / 128), 256, 0, stream>>>(xn_p, wqkv_p, b_qkv,
                                                             qn_g, qn_b, kn_g, kn_b,
                                                             qb, kb, vtb);
    attn<<<B_ * H_ * (N_ / 128), 128, 0, stream>>>(qb, kb, vtb, ao_p);
    gemm_proj<<<(M_ / 128) * (D_ / 128), 256, 0, stream>>>(ao_p, wproj_p, b_proj, out);
}

// Round 12
// 189.582 us; speedup vs baseline: 1.1798x; 1.0029x over previous
//
#include <hip/hip_runtime.h>

typedef _Float16 half8 __attribute__((ext_vector_type(8)));
typedef _Float16 half4 __attribute__((ext_vector_type(4)));
typedef _Float16 half2v __attribute__((ext_vector_type(2)));
typedef float f32x4 __attribute__((ext_vector_type(4)));

#define B_    16
#define N_    1024
#define D_    768
#define H_    12
#define M_    (B_ * N_)     // 16384
#define QKVN_ 2304
#define EPS_  1e-5f
#define QS_   0.18033688011112042f   // 0.125 * log2(e)

__device__ __forceinline__ float exp2_fast(float x) {
#if __has_builtin(__builtin_amdgcn_exp2f)
    return __builtin_amdgcn_exp2f(x);
#else
    return __builtin_exp2f(x);
#endif
}

// ---- A image (rows x 768): per (mt=row>>8, kt=k>>6) 16384-half tile:
//      [(t16=(row>>4)&15)*2 + ksub=(k>>5)&1][lg=(k>>3)&3][p=row&15][e=k&7]
__device__ __forceinline__ size_t aidx(int row, int d) {
    return ((size_t)((row >> 8) * 12 + (d >> 6))) * 16384
         + ((((row >> 4) & 15) * 2) + ((d >> 5) & 1)) * 512
         + (((d >> 3) & 3)) * 128 + (row & 15) * 8 + (d & 7);
}
// ---- B image (cols x 768): per (nt=n>>7, kt) 8192-half tile: [(t16=(n>>4)&7)*2+ksub][lg][p][e]

// ---------------- fused prep: weight pack (blocks 0..575) + embed LN (blocks 576+) --------
__global__ __launch_bounds__(256) void prep(const float* __restrict__ x,
                                            const float* __restrict__ ln_g,
                                            const float* __restrict__ ln_b,
                                            const float* __restrict__ Wqkv,
                                            const float* __restrict__ Wproj,
                                            _Float16* __restrict__ xp,
                                            _Float16* __restrict__ wqkv_p,
                                            _Float16* __restrict__ wproj_p) {
    __shared__ float T[64][65];
    int tb = blockIdx.x;
    if (tb < 576) {
        // ---- weight cast + B-image pack ----
        int t = tb;
        const float* W; _Float16* O; int NW, k0, n0;
        if (t < 432) { W = Wqkv;  O = wqkv_p;  NW = QKVN_; k0 = (t % 12) * 64; n0 = (t / 12) * 64; }
        else { t -= 432; W = Wproj; O = wproj_p; NW = D_;  k0 = (t % 12) * 64; n0 = (t / 12) * 64; }
        int c = threadIdx.x & 63, r4 = threadIdx.x >> 6;
#pragma unroll
        for (int i = 0; i < 16; ++i) {
            int k = i * 4 + r4;
            T[c][k] = W[(size_t)(k0 + k) * NW + n0 + c];
        }
        __syncthreads();
        int kt = k0 >> 6;
        int ntile = n0 >> 7;
        int t16base = (n0 >> 4) & 7;
#pragma unroll
        for (int it = 0; it < 2; ++it) {
            int g = it * 256 + threadIdx.x;
            int t16l = g >> 7, ksub = (g >> 6) & 1, lgI = (g >> 4) & 3, p = g & 15;
            half8 v;
#pragma unroll
            for (int e = 0; e < 8; ++e)
                v[e] = (_Float16)T[t16l * 16 + p][ksub * 32 + lgI * 8 + e];
            *(half8*)&O[((size_t)(ntile * 12 + kt)) * 8192 +
                        ((t16base + t16l) * 2 + ksub) * 512 + lgI * 128 + p * 8] = v;
        }
    } else {
        // ---- embed LayerNorm -> A image ----
        int row = tb - 576;
        int tid = threadIdx.x;
        const float2* xr = (const float2*)(x + (size_t)row * D_);
        float2 v0 = xr[tid];
        float2 v1 = make_float2(0.f, 0.f);
        if (tid < 128) v1 = xr[256 + tid];
        float s = v0.x + v0.y + v1.x + v1.y;
        float q = v0.x * v0.x + v0.y * v0.y + v1.x * v1.x + v1.y * v1.y;
#pragma unroll
        for (int m = 32; m >= 1; m >>= 1) {
            s += __shfl_xor(s, m);
            q += __shfl_xor(q, m);
        }
        float* ss = &T[0][0];
        float* qq = &T[0][8];
        int wave = tid >> 6;
        if ((tid & 63) == 0) { ss[wave] = s; qq[wave] = q; }
        __syncthreads();
        float S = ss[0] + ss[1] + ss[2] + ss[3];
        float Q = qq[0] + qq[1] + qq[2] + qq[3];
        float mean = S * (1.f / 768.f);
        float var  = Q * (1.f / 768.f) - mean * mean;
        float rstd = rsqrtf(var + EPS_);
        const float2* g2 = (const float2*)ln_g;
        const float2* b2 = (const float2*)ln_b;
        {
            int d0 = 2 * tid;
            float2 ga = g2[tid], ba = b2[tid];
            half2v w;
            w[0] = (_Float16)((v0.x - mean) * rstd * ga.x + ba.x);
            w[1] = (_Float16)((v0.y - mean) * rstd * ga.y + ba.y);
            *(half2v*)&xp[aidx(row, d0)] = w;
        }
        if (tid < 128) {
            int d0 = 512 + 2 * tid;
            float2 ga = g2[256 + tid], ba = b2[256 + tid];
            half2v w;
            w[0] = (_Float16)((v1.x - mean) * rstd * ga.x + ba.x);
            w[1] = (_Float16)((v1.y - mean) * rstd * ga.y + ba.y);
            *(half2v*)&xp[aidx(row, d0)] = w;
        }
    }
}

// ---------------- QKV GEMM: pure-register, dual-orientation epilogue (R10 best) ----------
__global__ __launch_bounds__(256, 3) void gemm_qkv(const _Float16* __restrict__ Xp,
                                                   const _Float16* __restrict__ Wp,
                                                   const float* __restrict__ bias,
                                                   const float* __restrict__ qn_g,
                                                   const float* __restrict__ qn_b,
                                                   const float* __restrict__ kn_g,
                                                   const float* __restrict__ kn_b,
                                                   _Float16* __restrict__ qo,
                                                   _Float16* __restrict__ ko,
                                                   _Float16* __restrict__ vt) {
    int xcd = blockIdx.x & 7, loc = blockIdx.x >> 3;     // 2304 = 8 XCD * (16 m * 18 n)
    int mblk = xcd * 16 + (loc & 15);                    // m fastest within XCD
    int nb = loc >> 4;                                   // 0..17
    int tid = threadIdx.x;
    int wid = tid >> 6, lane = tid & 63;
    int wm = wid >> 1, wn = wid & 1;
    int lg = lane >> 4, l15 = lane & 15;
    bool isV = (nb >= 12);

    const _Float16* pw = Wp + (size_t)nb * 98304 + (wn * 4) * 1024 + lane * 8;
    const _Float16* px = Xp + (size_t)(mblk >> 1) * 196608 +
                         ((mblk & 1) * 8 + wm * 4) * 1024 + lane * 8;

    f32x4 acc[4][4] = {};
    half8 xa0[4], wb0[4], xa1[4], wb1[4];
    auto ld = [&](half8 (&xa)[4], half8 (&wb)[4], int t) {
        int kt = t >> 1, ks = t & 1;
        size_t offW = (size_t)kt * 8192 + ks * 512;
        size_t offX = (size_t)kt * 16384 + ks * 512;
#pragma unroll
        for (int i = 0; i < 4; ++i) {
            xa[i] = *(const half8*)(px + i * 1024 + offX);
            wb[i] = *(const half8*)(pw + i * 1024 + offW);
        }
    };
    auto mmQK = [&](half8 (&xa)[4], half8 (&wb)[4]) {    // acc[ni][mi] = W x X^T
#pragma unroll
        for (int ni = 0; ni < 4; ++ni)
#pragma unroll
            for (int mi = 0; mi < 4; ++mi)
                acc[ni][mi] = __builtin_amdgcn_mfma_f32_16x16x32_f16(wb[ni], xa[mi], acc[ni][mi], 0, 0, 0);
    };
    auto mmV = [&](half8 (&xa)[4], half8 (&wb)[4]) {     // acc[mi][ni] = X x W^T
#pragma unroll
        for (int mi = 0; mi < 4; ++mi)
#pragma unroll
            for (int ni = 0; ni < 4; ++ni)
                acc[mi][ni] = __builtin_amdgcn_mfma_f32_16x16x32_f16(xa[mi], wb[ni], acc[mi][ni], 0, 0, 0);
    };

    ld(xa0, wb0, 0);
    if (isV) {
        for (int tt = 0; tt < 11; ++tt) {
            ld(xa1, wb1, 2 * tt + 1);
            mmV(xa0, wb0);
            ld(xa0, wb0, 2 * tt + 2);
            mmV(xa1, wb1);
        }
        ld(xa1, wb1, 23);
        mmV(xa0, wb0);
        mmV(xa1, wb1);
    } else {
        for (int tt = 0; tt < 11; ++tt) {
            ld(xa1, wb1, 2 * tt + 1);
            mmQK(xa0, wb0);
            ld(xa0, wb0, 2 * tt + 2);
            mmQK(xa1, wb1);
        }
        ld(xa1, wb1, 23);
        mmQK(xa0, wb0);
        mmQK(xa1, wb1);
    }

    int m0 = mblk * 128;
    int col0 = nb * 128 + wn * 64;

    if (isV) {
        int hcol = (col0 % 768) >> 6;
        float qkvb[4];
#pragma unroll
        for (int ni = 0; ni < 4; ++ni) qkvb[ni] = bias[col0 + ni * 16 + l15];
#pragma unroll
        for (int mi = 0; mi < 4; ++mi) {
            int r0 = m0 + wm * 64 + mi * 16 + lg * 4;
            int bidx = r0 >> 10, pos = r0 & 1023;
            int kvblk = pos >> 5, h = (pos >> 4) & 1, lgR = (pos >> 2) & 3;
            size_t vbase = ((size_t)(bidx * H_ + hcol) * 32 + kvblk) * 4;
#pragma unroll
            for (int ni = 0; ni < 4; ++ni) {
                half4 h4;
#pragma unroll
                for (int j = 0; j < 4; ++j) h4[j] = (_Float16)(acc[mi][ni][j] + qkvb[ni]);
                *(half4*)&vt[(vbase + ni) * 512 + lgR * 128 + l15 * 8 + h * 4] = h4;
            }
        }
    } else {
        int s = col0 / 768;
        int hcol = (col0 % 768) >> 6;
        const float* gg = (s == 0) ? qn_g : kn_g;
        const float* bv = (s == 0) ? qn_b : kn_b;
        _Float16* dst = (s == 0) ? qo : ko;
        float4 g4[4], b4[4], bi4[4];
#pragma unroll
        for (int ni = 0; ni < 4; ++ni) {
            g4[ni]  = *(const float4*)&gg[ni * 16 + lg * 4];
            b4[ni]  = *(const float4*)&bv[ni * 16 + lg * 4];
            bi4[ni] = *(const float4*)&bias[col0 + ni * 16 + lg * 4];
        }
        int posbase = m0 + wm * 64;
        int bidx = posbase >> 10;
        size_t bh0 = (size_t)(bidx * H_ + hcol) * 65536;
        float scl = (s == 0) ? QS_ : 1.0f;
#pragma unroll
        for (int mi = 0; mi < 4; ++mi) {
            float vv[4][4];
            float sm = 0.f, sq = 0.f;
#pragma unroll
            for (int ni = 0; ni < 4; ++ni)
#pragma unroll
                for (int j = 0; j < 4; ++j) {
                    float bvj = (j == 0) ? bi4[ni].x : (j == 1) ? bi4[ni].y : (j == 2) ? bi4[ni].z : bi4[ni].w;
                    float v = acc[ni][mi][j] + bvj;
                    vv[ni][j] = v;
                    sm += v;
                    sq += v * v;
                }
            sm += __shfl_xor(sm, 16); sq += __shfl_xor(sq, 16);
            sm += __shfl_xor(sm, 32); sq += __shfl_xor(sq, 32);
            float mean = sm * (1.f / 64.f);
            float var  = sq * (1.f / 64.f) - mean * mean;
            float rstd = rsqrtf(var + EPS_) * scl;
            int posL = ((posbase & 1023) + mi * 16);
            size_t obase = bh0 + (size_t)(posL >> 5) * 2048 + ((posL >> 4) & 1) * 1024
                         + l15 * 8 + (lg & 1) * 4;
#pragma unroll
            for (int ni = 0; ni < 4; ++ni) {
                half4 h4;
#pragma unroll
                for (int j = 0; j < 4; ++j) {
                    float gj = (j == 0) ? g4[ni].x : (j == 1) ? g4[ni].y : (j == 2) ? g4[ni].z : g4[ni].w;
                    float bj = (j == 0) ? b4[ni].x : (j == 1) ? b4[ni].y : (j == 2) ? b4[ni].z : b4[ni].w;
                    h4[j] = (_Float16)((vv[ni][j] - mean) * rstd * gj + bj * scl);
                }
                *(half4*)&dst[obase + (ni >> 1) * 512 + (((ni & 1) << 1) | (lg >> 1)) * 128] = h4;
            }
        }
    }
}

// ---------------- flash attention: kv-split (2 waves/64q, 512 kv each) + LDS combine -----
struct KV {
    half8 kf[2][2];
    half8 vf[4];
};

__device__ __forceinline__ void ldKV(KV& s, const _Float16* kp, const _Float16* vp, int kvblk) {
    const _Float16* kb = kp + (size_t)kvblk * 2048;
#pragma unroll
    for (int nh = 0; nh < 2; ++nh)
#pragma unroll
        for (int ks = 0; ks < 2; ++ks)
            s.kf[nh][ks] = *(const half8*)(kb + (nh * 2 + ks) * 512);
    const _Float16* vb = vp + (size_t)kvblk * 2048;
#pragma unroll
    for (int di = 0; di < 4; ++di)
        s.vf[di] = *(const half8*)(vb + di * 512);
}

__device__ __forceinline__ void blockKV(const KV& s, const half8 (&qf)[4][2],
                                        f32x4 (&oacc)[4][4], f32x4 (&lacc)[4],
                                        half8 ones) {
#pragma unroll
    for (int mi = 0; mi < 4; ++mi) {
        f32x4 a0 = {}, a1 = {};
#pragma unroll
        for (int ks = 0; ks < 2; ++ks) {
            a0 = __builtin_amdgcn_mfma_f32_16x16x32_f16(s.kf[0][ks], qf[mi][ks], a0, 0, 0, 0);
            a1 = __builtin_amdgcn_mfma_f32_16x16x32_f16(s.kf[1][ks], qf[mi][ks], a1, 0, 0, 0);
        }
        half8 pf;
#pragma unroll
        for (int j = 0; j < 4; ++j) {
            pf[j]     = (_Float16)exp2_fast(a0[j]);
            pf[j + 4] = (_Float16)exp2_fast(a1[j]);
        }
        lacc[mi] = __builtin_amdgcn_mfma_f32_16x16x32_f16(ones, pf, lacc[mi], 0, 0, 0);
#pragma unroll
        for (int di = 0; di < 4; ++di)
            oacc[mi][di] = __builtin_amdgcn_mfma_f32_16x16x32_f16(s.vf[di], pf, oacc[mi][di], 0, 0, 0);
    }
}

__global__ __launch_bounds__(128, 2) void attn(const _Float16* __restrict__ qg,
                                               const _Float16* __restrict__ kg,
                                               const _Float16* __restrict__ vtg,
                                               _Float16* __restrict__ op) {
    __shared__ float OB[4][4][4][4][16];   // [mi][di][j][lg][l15] — lane-linear, conflict-free
    __shared__ float LB[4][16];
    int bphys = blockIdx.x;                          // 0..3071
    int jj = (bphys & 7) * 384 + (bphys >> 3);       // XCD-bijective (3072 = 8*384)
    int bh = jj >> 4, qgi = jj & 15;
    int b = bh / H_, h = bh % H_;
    int tid = threadIdx.x;
    int wid = tid >> 6, lane = tid & 63;
    int lg = lane >> 4, l15 = lane & 15;
    int qw0 = qgi * 64;

    // Q from Q-pack: coalesced fragment reads (both waves load the same 64 q-rows)
    const _Float16* qp2 = qg + (size_t)bh * 65536 + (size_t)(qw0 >> 5) * 2048 + lane * 8;
    half8 qf[4][2];
#pragma unroll
    for (int mi = 0; mi < 4; ++mi)
#pragma unroll
        for (int ks = 0; ks < 2; ++ks)
            qf[mi][ks] = *(const half8*)(qp2 + (mi >> 1) * 2048 + (mi & 1) * 1024 + ks * 512);

    const _Float16* kp = kg + (size_t)bh * 65536 + lane * 8;
    const _Float16* vp = vtg + (size_t)bh * 65536 + lane * 8;
    int kvbase = wid * 16;                           // wave 0: kvblk 0..15, wave 1: 16..31

    half8 ones;
#pragma unroll
    for (int i = 0; i < 8; ++i) ones[i] = (_Float16)1.0f;

    f32x4 oacc[4][4] = {};
    f32x4 lacc[4] = {};

    KV s0, s1;
    ldKV(s0, kp, vp, kvbase);
    for (int t = 0; t < 8; ++t) {
        ldKV(s1, kp, vp, kvbase + ((2 * t + 1) & 15));
        blockKV(s0, qf, oacc, lacc, ones);
        ldKV(s0, kp, vp, kvbase + ((2 * t + 2) & 15));  // wraps harmlessly on last iter
        blockKV(s1, qf, oacc, lacc, ones);
    }

    // combine: wave 1 spills partials, wave 0 adds and stores
    if (wid == 1) {
#pragma unroll
        for (int mi = 0; mi < 4; ++mi) {
#pragma unroll
            for (int di = 0; di < 4; ++di)
#pragma unroll
                for (int j = 0; j < 4; ++j)
                    OB[mi][di][j][lg][l15] = oacc[mi][di][j];
            if (lg == 0) LB[mi][l15] = lacc[mi][0];
        }
    }
    __syncthreads();
    if (wid == 0) {
#pragma unroll
        for (int mi = 0; mi < 4; ++mi) {
            float inv = 1.f / (lacc[mi][0] + LB[mi][l15]);
            int row0 = b * 1024 + qw0 + mi * 16;
            int mtv = row0 >> 8, t16 = (row0 >> 4) & 15;
#pragma unroll
            for (int di = 0; di < 4; ++di) {
                half4 h4;
#pragma unroll
                for (int j = 0; j < 4; ++j)
                    h4[j] = (_Float16)((oacc[mi][di][j] + OB[mi][di][j][lg][l15]) * inv);
                size_t o = ((size_t)(mtv * 12 + h)) * 16384 + (t16 * 2 + (di >> 1)) * 512
                         + ((di & 1) * 2 + (lg >> 1)) * 128 + l15 * 8 + (lg & 1) * 4;
                *(half4*)&op[o] = h4;
            }
        }
    }
}

// ---------------- proj GEMM: pure-register from images (R10 structure, unchanged) --------
__global__ __launch_bounds__(256, 3) void gemm_proj(const _Float16* __restrict__ Ap,
                                                    const _Float16* __restrict__ Wp,
                                                    const float* __restrict__ bias,
                                                    float* __restrict__ out) {
    int xcd = blockIdx.x & 7, loc = blockIdx.x >> 3;     // 768 = 8 XCD * (16 m * 6 n)
    int mblk = xcd * 16 + (loc & 15);
    int nb = loc >> 4;                                   // 0..5
    int tid = threadIdx.x;
    int wid = tid >> 6, lane = tid & 63;
    int wm = wid >> 1, wn = wid & 1;
    int lg = lane >> 4, l15 = lane & 15;

    const _Float16* pw = Wp + (size_t)nb * 98304 + (wn * 4) * 1024 + lane * 8;
    const _Float16* px = Ap + (size_t)(mblk >> 1) * 196608 +
                         ((mblk & 1) * 8 + wm * 4) * 1024 + lane * 8;

    f32x4 acc[4][4] = {};
    half8 xa0[4], wb0[4], xa1[4], wb1[4];
    auto ld = [&](half8 (&xa)[4], half8 (&wb)[4], int t) {
        int kt = t >> 1, ks = t & 1;
        size_t offW = (size_t)kt * 8192 + ks * 512;
        size_t offX = (size_t)kt * 16384 + ks * 512;
#pragma unroll
        for (int i = 0; i < 4; ++i) {
            xa[i] = *(const half8*)(px + i * 1024 + offX);
            wb[i] = *(const half8*)(pw + i * 1024 + offW);
        }
    };
    auto mm = [&](half8 (&xa)[4], half8 (&wb)[4]) {
#pragma unroll
        for (int mi = 0; mi < 4; ++mi)
#pragma unroll
            for (int ni = 0; ni < 4; ++ni)
                acc[mi][ni] = __builtin_amdgcn_mfma_f32_16x16x32_f16(xa[mi], wb[ni], acc[mi][ni], 0, 0, 0);
    };
    ld(xa0, wb0, 0);
    for (int tt = 0; tt < 11; ++tt) {
        ld(xa1, wb1, 2 * tt + 1);
        mm(xa0, wb0);
        ld(xa0, wb0, 2 * tt + 2);
        mm(xa1, wb1);
    }
    ld(xa1, wb1, 23);
    mm(xa0, wb0);
    mm(xa1, wb1);

    int m0 = mblk * 128, n0 = nb * 128;
#pragma unroll
    for (int mi = 0; mi < 4; ++mi)
#pragma unroll
        for (int ni = 0; ni < 4; ++ni) {
            int col = n0 + wn * 64 + ni * 16 + l15;
            float bv = bias[col];
#pragma unroll
            for (int j = 0; j < 4; ++j) {
                int row = m0 + wm * 64 + mi * 16 + lg * 4 + j;
                out[(size_t)row * D_ + col] = acc[mi][ni][j] + bv;
            }
        }
}

// ---------------- launch ----------------
extern "C" void kernel_launch(void* const* d_in, const int* in_sizes, int n_in,
                              void* d_out, int out_size, void* d_ws, size_t ws_size,
                              hipStream_t stream) {
    const float* x      = (const float*)d_in[0];
    const float* ln_g   = (const float*)d_in[1];
    const float* ln_b   = (const float*)d_in[2];
    const float* W_qkv  = (const float*)d_in[3];
    const float* b_qkv  = (const float*)d_in[4];
    const float* qn_g   = (const float*)d_in[5];
    const float* qn_b   = (const float*)d_in[6];
    const float* kn_g   = (const float*)d_in[7];
    const float* kn_b   = (const float*)d_in[8];
    const float* W_proj = (const float*)d_in[9];
    const float* b_proj = (const float*)d_in[10];
    float* out = (float*)d_out;
    char* ws = (char*)d_ws;

    constexpr size_t XN_SZ    = (size_t)M_ * D_ * 2;
    constexpr size_t WQKVT_SZ = (size_t)QKVN_ * D_ * 2;
    constexpr size_t WPROJT_SZ= (size_t)D_ * D_ * 2;
    constexpr size_t HEAD_SZ  = (size_t)B_ * H_ * N_ * 64 * 2;

    _Float16* xn_p   = (_Float16*)(ws);                      // A image; reused as proj-A image
    _Float16* wqkv_p = (_Float16*)(ws + XN_SZ);              // B image (2304 cols)
    _Float16* wproj_p= (_Float16*)(ws + XN_SZ + WQKVT_SZ);   // B image (768 cols)
    _Float16* qb     = (_Float16*)(ws + XN_SZ + WQKVT_SZ + WPROJT_SZ);  // Q pack
    _Float16* kb     = (_Float16*)((char*)qb + HEAD_SZ);     // K pack
    _Float16* vtb    = (_Float16*)((char*)kb + HEAD_SZ);     // V pack
    _Float16* ao_p   = xn_p;                                 // xn dead after gemm_qkv

    prep<<<576 + M_, 256, 0, stream>>>(x, ln_g, ln_b, W_qkv, W_proj,
                                       xn_p, wqkv_p, wproj_p);
    gemm_qkv<<<(M_ / 128) * (QKVN_ / 128), 256, 0, stream>>>(xn_p, wqkv_p, b_qkv,
                                                             qn_g, qn_b, kn_g, kn_b,
                                                             qb, kb, vtb);
    attn<<<B_ * H_ * (N_ / 64), 128, 0, stream>>>(qb, kb, vtb, ao_p);
    gemm_proj<<<(M_ / 128) * (D_ / 128), 256, 0, stream>>>(ao_p, wproj_p, b_proj, out);
}

// Round 13
// 188.286 us; speedup vs baseline: 1.1879x; 1.0069x over previous
//
#include <hip/hip_runtime.h>

typedef _Float16 half8 __attribute__((ext_vector_type(8)));
typedef _Float16 half4 __attribute__((ext_vector_type(4)));
typedef _Float16 half2v __attribute__((ext_vector_type(2)));
typedef float f32x4 __attribute__((ext_vector_type(4)));

#define B_    16
#define N_    1024
#define D_    768
#define H_    12
#define M_    (B_ * N_)     // 16384
#define QKVN_ 2304
#define EPS_  1e-5f
#define QS_   0.18033688011112042f   // 0.125 * log2(e)

__device__ __forceinline__ float exp2_fast(float x) {
#if __has_builtin(__builtin_amdgcn_exp2f)
    return __builtin_amdgcn_exp2f(x);
#else
    return __builtin_exp2f(x);
#endif
}

// ---- A image (rows x 768): per (mt=row>>8, kt=k>>6) 16384-half tile:
//      [(t16=(row>>4)&15)*2 + ksub=(k>>5)&1][lg=(k>>3)&3][p=row&15][e=k&7]
__device__ __forceinline__ size_t aidx(int row, int d) {
    return ((size_t)((row >> 8) * 12 + (d >> 6))) * 16384
         + ((((row >> 4) & 15) * 2) + ((d >> 5) & 1)) * 512
         + (((d >> 3) & 3)) * 128 + (row & 15) * 8 + (d & 7);
}
// ---- B image (cols x 768): per (nt=n>>7, kt) 8192-half tile: [(t16=(n>>4)&7)*2+ksub][lg][p][e]

// ---------------- fused prep: weight pack (blocks 0..575) + embed LN (blocks 576+) --------
__global__ __launch_bounds__(256) void prep(const float* __restrict__ x,
                                            const float* __restrict__ ln_g,
                                            const float* __restrict__ ln_b,
                                            const float* __restrict__ Wqkv,
                                            const float* __restrict__ Wproj,
                                            _Float16* __restrict__ xp,
                                            _Float16* __restrict__ wqkv_p,
                                            _Float16* __restrict__ wproj_p) {
    __shared__ float T[64][65];
    int tb = blockIdx.x;
    if (tb < 576) {
        int t = tb;
        const float* W; _Float16* O; int NW, k0, n0;
        if (t < 432) { W = Wqkv;  O = wqkv_p;  NW = QKVN_; k0 = (t % 12) * 64; n0 = (t / 12) * 64; }
        else { t -= 432; W = Wproj; O = wproj_p; NW = D_;  k0 = (t % 12) * 64; n0 = (t / 12) * 64; }
        int c = threadIdx.x & 63, r4 = threadIdx.x >> 6;
#pragma unroll
        for (int i = 0; i < 16; ++i) {
            int k = i * 4 + r4;
            T[c][k] = W[(size_t)(k0 + k) * NW + n0 + c];
        }
        __syncthreads();
        int kt = k0 >> 6;
        int ntile = n0 >> 7;
        int t16base = (n0 >> 4) & 7;
#pragma unroll
        for (int it = 0; it < 2; ++it) {
            int g = it * 256 + threadIdx.x;
            int t16l = g >> 7, ksub = (g >> 6) & 1, lgI = (g >> 4) & 3, p = g & 15;
            half8 v;
#pragma unroll
            for (int e = 0; e < 8; ++e)
                v[e] = (_Float16)T[t16l * 16 + p][ksub * 32 + lgI * 8 + e];
            *(half8*)&O[((size_t)(ntile * 12 + kt)) * 8192 +
                        ((t16base + t16l) * 2 + ksub) * 512 + lgI * 128 + p * 8] = v;
        }
    } else {
        int row = tb - 576;
        int tid = threadIdx.x;
        const float2* xr = (const float2*)(x + (size_t)row * D_);
        float2 v0 = xr[tid];
        float2 v1 = make_float2(0.f, 0.f);
        if (tid < 128) v1 = xr[256 + tid];
        float s = v0.x + v0.y + v1.x + v1.y;
        float q = v0.x * v0.x + v0.y * v0.y + v1.x * v1.x + v1.y * v1.y;
#pragma unroll
        for (int m = 32; m >= 1; m >>= 1) {
            s += __shfl_xor(s, m);
            q += __shfl_xor(q, m);
        }
        float* ss = &T[0][0];
        float* qq = &T[0][8];
        int wave = tid >> 6;
        if ((tid & 63) == 0) { ss[wave] = s; qq[wave] = q; }
        __syncthreads();
        float S = ss[0] + ss[1] + ss[2] + ss[3];
        float Q = qq[0] + qq[1] + qq[2] + qq[3];
        float mean = S * (1.f / 768.f);
        float var  = Q * (1.f / 768.f) - mean * mean;
        float rstd = rsqrtf(var + EPS_);
        const float2* g2 = (const float2*)ln_g;
        const float2* b2 = (const float2*)ln_b;
        {
            int d0 = 2 * tid;
            float2 ga = g2[tid], ba = b2[tid];
            half2v w;
            w[0] = (_Float16)((v0.x - mean) * rstd * ga.x + ba.x);
            w[1] = (_Float16)((v0.y - mean) * rstd * ga.y + ba.y);
            *(half2v*)&xp[aidx(row, d0)] = w;
        }
        if (tid < 128) {
            int d0 = 512 + 2 * tid;
            float2 ga = g2[256 + tid], ba = b2[256 + tid];
            half2v w;
            w[0] = (_Float16)((v1.x - mean) * rstd * ga.x + ba.x);
            w[1] = (_Float16)((v1.y - mean) * rstd * ga.y + ba.y);
            *(half2v*)&xp[aidx(row, d0)] = w;
        }
    }
}

// ---------------- QKV GEMM: pure-register, dual-orientation epilogue (R11 best, frozen) ---
__global__ __launch_bounds__(256, 3) void gemm_qkv(const _Float16* __restrict__ Xp,
                                                   const _Float16* __restrict__ Wp,
                                                   const float* __restrict__ bias,
                                                   const float* __restrict__ qn_g,
                                                   const float* __restrict__ qn_b,
                                                   const float* __restrict__ kn_g,
                                                   const float* __restrict__ kn_b,
                                                   _Float16* __restrict__ qo,
                                                   _Float16* __restrict__ ko,
                                                   _Float16* __restrict__ vt) {
    int xcd = blockIdx.x & 7, loc = blockIdx.x >> 3;     // 2304 = 8 XCD * (16 m * 18 n)
    int mblk = xcd * 16 + (loc & 15);                    // m fastest within XCD
    int nb = loc >> 4;                                   // 0..17
    int tid = threadIdx.x;
    int wid = tid >> 6, lane = tid & 63;
    int wm = wid >> 1, wn = wid & 1;
    int lg = lane >> 4, l15 = lane & 15;
    bool isV = (nb >= 12);

    const _Float16* pw = Wp + (size_t)nb * 98304 + (wn * 4) * 1024 + lane * 8;
    const _Float16* px = Xp + (size_t)(mblk >> 1) * 196608 +
                         ((mblk & 1) * 8 + wm * 4) * 1024 + lane * 8;

    f32x4 acc[4][4] = {};
    half8 xa0[4], wb0[4], xa1[4], wb1[4];
    auto ld = [&](half8 (&xa)[4], half8 (&wb)[4], int t) {
        int kt = t >> 1, ks = t & 1;
        size_t offW = (size_t)kt * 8192 + ks * 512;
        size_t offX = (size_t)kt * 16384 + ks * 512;
#pragma unroll
        for (int i = 0; i < 4; ++i) {
            xa[i] = *(const half8*)(px + i * 1024 + offX);
            wb[i] = *(const half8*)(pw + i * 1024 + offW);
        }
    };
    auto mmQK = [&](half8 (&xa)[4], half8 (&wb)[4]) {    // acc[ni][mi] = W x X^T
#pragma unroll
        for (int ni = 0; ni < 4; ++ni)
#pragma unroll
            for (int mi = 0; mi < 4; ++mi)
                acc[ni][mi] = __builtin_amdgcn_mfma_f32_16x16x32_f16(wb[ni], xa[mi], acc[ni][mi], 0, 0, 0);
    };
    auto mmV = [&](half8 (&xa)[4], half8 (&wb)[4]) {     // acc[mi][ni] = X x W^T
#pragma unroll
        for (int mi = 0; mi < 4; ++mi)
#pragma unroll
            for (int ni = 0; ni < 4; ++ni)
                acc[mi][ni] = __builtin_amdgcn_mfma_f32_16x16x32_f16(xa[mi], wb[ni], acc[mi][ni], 0, 0, 0);
    };

    ld(xa0, wb0, 0);
    if (isV) {
        for (int tt = 0; tt < 11; ++tt) {
            ld(xa1, wb1, 2 * tt + 1);
            mmV(xa0, wb0);
            ld(xa0, wb0, 2 * tt + 2);
            mmV(xa1, wb1);
        }
        ld(xa1, wb1, 23);
        mmV(xa0, wb0);
        mmV(xa1, wb1);
    } else {
        for (int tt = 0; tt < 11; ++tt) {
            ld(xa1, wb1, 2 * tt + 1);
            mmQK(xa0, wb0);
            ld(xa0, wb0, 2 * tt + 2);
            mmQK(xa1, wb1);
        }
        ld(xa1, wb1, 23);
        mmQK(xa0, wb0);
        mmQK(xa1, wb1);
    }

    int m0 = mblk * 128;
    int col0 = nb * 128 + wn * 64;

    if (isV) {
        int hcol = (col0 % 768) >> 6;
        float qkvb[4];
#pragma unroll
        for (int ni = 0; ni < 4; ++ni) qkvb[ni] = bias[col0 + ni * 16 + l15];
#pragma unroll
        for (int mi = 0; mi < 4; ++mi) {
            int r0 = m0 + wm * 64 + mi * 16 + lg * 4;
            int bidx = r0 >> 10, pos = r0 & 1023;
            int kvblk = pos >> 5, h = (pos >> 4) & 1, lgR = (pos >> 2) & 3;
            size_t vbase = ((size_t)(bidx * H_ + hcol) * 32 + kvblk) * 4;
#pragma unroll
            for (int ni = 0; ni < 4; ++ni) {
                half4 h4;
#pragma unroll
                for (int j = 0; j < 4; ++j) h4[j] = (_Float16)(acc[mi][ni][j] + qkvb[ni]);
                *(half4*)&vt[(vbase + ni) * 512 + lgR * 128 + l15 * 8 + h * 4] = h4;
            }
        }
    } else {
        int s = col0 / 768;
        int hcol = (col0 % 768) >> 6;
        const float* gg = (s == 0) ? qn_g : kn_g;
        const float* bv = (s == 0) ? qn_b : kn_b;
        _Float16* dst = (s == 0) ? qo : ko;
        float4 g4[4], b4[4], bi4[4];
#pragma unroll
        for (int ni = 0; ni < 4; ++ni) {
            g4[ni]  = *(const float4*)&gg[ni * 16 + lg * 4];
            b4[ni]  = *(const float4*)&bv[ni * 16 + lg * 4];
            bi4[ni] = *(const float4*)&bias[col0 + ni * 16 + lg * 4];
        }
        int posbase = m0 + wm * 64;
        int bidx = posbase >> 10;
        size_t bh0 = (size_t)(bidx * H_ + hcol) * 65536;
        float scl = (s == 0) ? QS_ : 1.0f;
#pragma unroll
        for (int mi = 0; mi < 4; ++mi) {
            float vv[4][4];
            float sm = 0.f, sq = 0.f;
#pragma unroll
            for (int ni = 0; ni < 4; ++ni)
#pragma unroll
                for (int j = 0; j < 4; ++j) {
                    float bvj = (j == 0) ? bi4[ni].x : (j == 1) ? bi4[ni].y : (j == 2) ? bi4[ni].z : bi4[ni].w;
                    float v = acc[ni][mi][j] + bvj;
                    vv[ni][j] = v;
                    sm += v;
                    sq += v * v;
                }
            sm += __shfl_xor(sm, 16); sq += __shfl_xor(sq, 16);
            sm += __shfl_xor(sm, 32); sq += __shfl_xor(sq, 32);
            float mean = sm * (1.f / 64.f);
            float var  = sq * (1.f / 64.f) - mean * mean;
            float rstd = rsqrtf(var + EPS_) * scl;
            int posL = ((posbase & 1023) + mi * 16);
            size_t obase = bh0 + (size_t)(posL >> 5) * 2048 + ((posL >> 4) & 1) * 1024
                         + l15 * 8 + (lg & 1) * 4;
#pragma unroll
            for (int ni = 0; ni < 4; ++ni) {
                half4 h4;
#pragma unroll
                for (int j = 0; j < 4; ++j) {
                    float gj = (j == 0) ? g4[ni].x : (j == 1) ? g4[ni].y : (j == 2) ? g4[ni].z : g4[ni].w;
                    float bj = (j == 0) ? b4[ni].x : (j == 1) ? b4[ni].y : (j == 2) ? b4[ni].z : b4[ni].w;
                    h4[j] = (_Float16)((vv[ni][j] - mean) * rstd * gj + bj * scl);
                }
                *(half4*)&dst[obase + (ni >> 1) * 512 + (((ni & 1) << 1) | (lg >> 1)) * 128] = h4;
            }
        }
    }
}

// ---------------- flash attention: kv-split + LDS combine + setprio on MFMA clusters -----
struct KV {
    half8 kf[2][2];
    half8 vf[4];
};

__device__ __forceinline__ void ldKV(KV& s, const _Float16* kp, const _Float16* vp, int kvblk) {
    const _Float16* kb = kp + (size_t)kvblk * 2048;
#pragma unroll
    for (int nh = 0; nh < 2; ++nh)
#pragma unroll
        for (int ks = 0; ks < 2; ++ks)
            s.kf[nh][ks] = *(const half8*)(kb + (nh * 2 + ks) * 512);
    const _Float16* vb = vp + (size_t)kvblk * 2048;
#pragma unroll
    for (int di = 0; di < 4; ++di)
        s.vf[di] = *(const half8*)(vb + di * 512);
}

__device__ __forceinline__ void blockKV(const KV& s, const half8 (&qf)[4][2],
                                        f32x4 (&oacc)[4][4], f32x4 (&lacc)[4],
                                        half8 ones) {
#pragma unroll
    for (int mi = 0; mi < 4; ++mi) {
        f32x4 a0 = {}, a1 = {};
        __builtin_amdgcn_s_setprio(1);
#pragma unroll
        for (int ks = 0; ks < 2; ++ks) {
            a0 = __builtin_amdgcn_mfma_f32_16x16x32_f16(s.kf[0][ks], qf[mi][ks], a0, 0, 0, 0);
            a1 = __builtin_amdgcn_mfma_f32_16x16x32_f16(s.kf[1][ks], qf[mi][ks], a1, 0, 0, 0);
        }
        __builtin_amdgcn_s_setprio(0);
        half8 pf;
#pragma unroll
        for (int j = 0; j < 4; ++j) {
            pf[j]     = (_Float16)exp2_fast(a0[j]);
            pf[j + 4] = (_Float16)exp2_fast(a1[j]);
        }
        __builtin_amdgcn_s_setprio(1);
        lacc[mi] = __builtin_amdgcn_mfma_f32_16x16x32_f16(ones, pf, lacc[mi], 0, 0, 0);
#pragma unroll
        for (int di = 0; di < 4; ++di)
            oacc[mi][di] = __builtin_amdgcn_mfma_f32_16x16x32_f16(s.vf[di], pf, oacc[mi][di], 0, 0, 0);
        __builtin_amdgcn_s_setprio(0);
    }
}

__global__ __launch_bounds__(128, 2) void attn(const _Float16* __restrict__ qg,
                                               const _Float16* __restrict__ kg,
                                               const _Float16* __restrict__ vtg,
                                               _Float16* __restrict__ op) {
    __shared__ float OB[4][4][4][4][16];   // [mi][di][j][lg][l15] — lane-linear, conflict-free
    __shared__ float LB[4][16];
    int bphys = blockIdx.x;                          // 0..3071
    int jj = (bphys & 7) * 384 + (bphys >> 3);       // XCD-bijective (3072 = 8*384)
    int bh = jj >> 4, qgi = jj & 15;
    int b = bh / H_, h = bh % H_;
    int tid = threadIdx.x;
    int wid = tid >> 6, lane = tid & 63;
    int lg = lane >> 4, l15 = lane & 15;
    int qw0 = qgi * 64;

    const _Float16* qp2 = qg + (size_t)bh * 65536 + (size_t)(qw0 >> 5) * 2048 + lane * 8;
    half8 qf[4][2];
#pragma unroll
    for (int mi = 0; mi < 4; ++mi)
#pragma unroll
        for (int ks = 0; ks < 2; ++ks)
            qf[mi][ks] = *(const half8*)(qp2 + (mi >> 1) * 2048 + (mi & 1) * 1024 + ks * 512);

    const _Float16* kp = kg + (size_t)bh * 65536 + lane * 8;
    const _Float16* vp = vtg + (size_t)bh * 65536 + lane * 8;
    int kvbase = wid * 16;

    half8 ones;
#pragma unroll
    for (int i = 0; i < 8; ++i) ones[i] = (_Float16)1.0f;

    f32x4 oacc[4][4] = {};
    f32x4 lacc[4] = {};

    KV s0, s1;
    ldKV(s0, kp, vp, kvbase);
    for (int t = 0; t < 8; ++t) {
        ldKV(s1, kp, vp, kvbase + ((2 * t + 1) & 15));
        blockKV(s0, qf, oacc, lacc, ones);
        ldKV(s0, kp, vp, kvbase + ((2 * t + 2) & 15));
        blockKV(s1, qf, oacc, lacc, ones);
    }

    if (wid == 1) {
#pragma unroll
        for (int mi = 0; mi < 4; ++mi) {
#pragma unroll
            for (int di = 0; di < 4; ++di)
#pragma unroll
                for (int j = 0; j < 4; ++j)
                    OB[mi][di][j][lg][l15] = oacc[mi][di][j];
            if (lg == 0) LB[mi][l15] = lacc[mi][0];
        }
    }
    __syncthreads();
    if (wid == 0) {
#pragma unroll
        for (int mi = 0; mi < 4; ++mi) {
            float inv = 1.f / (lacc[mi][0] + LB[mi][l15]);
            int row0 = b * 1024 + qw0 + mi * 16;
            int mtv = row0 >> 8, t16 = (row0 >> 4) & 15;
#pragma unroll
            for (int di = 0; di < 4; ++di) {
                half4 h4;
#pragma unroll
                for (int j = 0; j < 4; ++j)
                    h4[j] = (_Float16)((oacc[mi][di][j] + OB[mi][di][j][lg][l15]) * inv);
                size_t o = ((size_t)(mtv * 12 + h)) * 16384 + (t16 * 2 + (di >> 1)) * 512
                         + ((di & 1) * 2 + (lg >> 1)) * 128 + l15 * 8 + (lg & 1) * 4;
                *(half4*)&op[o] = h4;
            }
        }
    }
}

// ---------------- proj GEMM: pure-register, SWAPPED orientation -> float4 stores ----------
// mfma(W, X): lane col = output row(pos), regs j = output col d -> each lane holds 4
// consecutive out-cols => 16 float4 stores/thread (was 64 scalar). Same math/order.
__global__ __launch_bounds__(256, 3) void gemm_proj(const _Float16* __restrict__ Ap,
                                                    const _Float16* __restrict__ Wp,
                                                    const float* __restrict__ bias,
                                                    float* __restrict__ out) {
    int xcd = blockIdx.x & 7, loc = blockIdx.x >> 3;     // 768 = 8 XCD * (16 m * 6 n)
    int mblk = xcd * 16 + (loc & 15);
    int nb = loc >> 4;                                   // 0..5
    int tid = threadIdx.x;
    int wid = tid >> 6, lane = tid & 63;
    int wm = wid >> 1, wn = wid & 1;
    int lg = lane >> 4, l15 = lane & 15;

    const _Float16* pw = Wp + (size_t)nb * 98304 + (wn * 4) * 1024 + lane * 8;
    const _Float16* px = Ap + (size_t)(mblk >> 1) * 196608 +
                         ((mblk & 1) * 8 + wm * 4) * 1024 + lane * 8;

    f32x4 acc[4][4] = {};                                // acc[ni][mi]
    half8 xa0[4], wb0[4], xa1[4], wb1[4];
    auto ld = [&](half8 (&xa)[4], half8 (&wb)[4], int t) {
        int kt = t >> 1, ks = t & 1;
        size_t offW = (size_t)kt * 8192 + ks * 512;
        size_t offX = (size_t)kt * 16384 + ks * 512;
#pragma unroll
        for (int i = 0; i < 4; ++i) {
            xa[i] = *(const half8*)(px + i * 1024 + offX);
            wb[i] = *(const half8*)(pw + i * 1024 + offW);
        }
    };
    auto mm = [&](half8 (&xa)[4], half8 (&wb)[4]) {      // swapped: acc[ni][mi] = W x X^T
#pragma unroll
        for (int ni = 0; ni < 4; ++ni)
#pragma unroll
            for (int mi = 0; mi < 4; ++mi)
                acc[ni][mi] = __builtin_amdgcn_mfma_f32_16x16x32_f16(wb[ni], xa[mi], acc[ni][mi], 0, 0, 0);
    };
    ld(xa0, wb0, 0);
    for (int tt = 0; tt < 11; ++tt) {
        ld(xa1, wb1, 2 * tt + 1);
        mm(xa0, wb0);
        ld(xa0, wb0, 2 * tt + 2);
        mm(xa1, wb1);
    }
    ld(xa1, wb1, 23);
    mm(xa0, wb0);
    mm(xa1, wb1);

    int m0 = mblk * 128, n0 = nb * 128;
#pragma unroll
    for (int ni = 0; ni < 4; ++ni) {
        int colb = n0 + wn * 64 + ni * 16 + lg * 4;      // float4-aligned out-col base
        float4 bv4 = *(const float4*)&bias[colb];
#pragma unroll
        for (int mi = 0; mi < 4; ++mi) {
            int row = m0 + wm * 64 + mi * 16 + l15;      // lane col = pos
            float4 o4;
            o4.x = acc[ni][mi][0] + bv4.x;
            o4.y = acc[ni][mi][1] + bv4.y;
            o4.z = acc[ni][mi][2] + bv4.z;
            o4.w = acc[ni][mi][3] + bv4.w;
            *(float4*)&out[(size_t)row * D_ + colb] = o4;
        }
    }
}

// ---------------- launch ----------------
extern "C" void kernel_launch(void* const* d_in, const int* in_sizes, int n_in,
                              void* d_out, int out_size, void* d_ws, size_t ws_size,
                              hipStream_t stream) {
    const float* x      = (const float*)d_in[0];
    const float* ln_g   = (const float*)d_in[1];
    const float* ln_b   = (const float*)d_in[2];
    const float* W_qkv  = (const float*)d_in[3];
    const float* b_qkv  = (const float*)d_in[4];
    const float* qn_g   = (const float*)d_in[5];
    const float* qn_b   = (const float*)d_in[6];
    const float* kn_g   = (const float*)d_in[7];
    const float* kn_b   = (const float*)d_in[8];
    const float* W_proj = (const float*)d_in[9];
    const float* b_proj = (const float*)d_in[10];
    float* out = (float*)d_out;
    char* ws = (char*)d_ws;

    constexpr size_t XN_SZ    = (size_t)M_ * D_ * 2;
    constexpr size_t WQKVT_SZ = (size_t)QKVN_ * D_ * 2;
    constexpr size_t WPROJT_SZ= (size_t)D_ * D_ * 2;
    constexpr size_t HEAD_SZ  = (size_t)B_ * H_ * N_ * 64 * 2;

    _Float16* xn_p   = (_Float16*)(ws);                      // A image; reused as proj-A image
    _Float16* wqkv_p = (_Float16*)(ws + XN_SZ);              // B image (2304 cols)
    _Float16* wproj_p= (_Float16*)(ws + XN_SZ + WQKVT_SZ);   // B image (768 cols)
    _Float16* qb     = (_Float16*)(ws + XN_SZ + WQKVT_SZ + WPROJT_SZ);  // Q pack
    _Float16* kb     = (_Float16*)((char*)qb + HEAD_SZ);     // K pack
    _Float16* vtb    = (_Float16*)((char*)kb + HEAD_SZ);     // V pack
    _Float16* ao_p   = xn_p;                                 // xn dead after gemm_qkv

    prep<<<576 + M_, 256, 0, stream>>>(x, ln_g, ln_b, W_qkv, W_proj,
                                       xn_p, wqkv_p, wproj_p);
    gemm_qkv<<<(M_ / 128) * (QKVN_ / 128), 256, 0, stream>>>(xn_p, wqkv_p, b_qkv,
                                                             qn_g, qn_b, kn_g, kn_b,
                                                             qb, kb, vtb);
    attn<<<B_ * H_ * (N_ / 64), 128, 0, stream>>>(qb, kb, vtb, ao_p);
    gemm_proj<<<(M_ / 128) * (D_ / 128), 256, 0, stream>>>(ao_p, wproj_p, b_proj, out);
}